// Round 2
// baseline (4000.491 us; speedup 1.0000x reference)
//
#include <hip/hip_runtime.h>
#include <hip/hip_bf16.h>

static __device__ __forceinline__ unsigned short f2bf(float f) {
  __hip_bfloat16 b = __float2bfloat16(f);  // round-to-nearest-even
  return *reinterpret_cast<unsigned short*>(&b);
}
static __device__ __forceinline__ float bf2f(unsigned short u) {
  unsigned int x = ((unsigned int)u) << 16;
  return __builtin_bit_cast(float, x);
}

// ---------------- degree accumulation (atomic +1 over dst) ----------------
__global__ __launch_bounds__(256) void k_deg(const int* __restrict__ ei,
                                             float* __restrict__ deg, int E) {
  int stride = gridDim.x * blockDim.x;
  for (int i = blockIdx.x * blockDim.x + threadIdx.x; i < E; i += stride)
    atomicAdd(&deg[ei[E + i]], 1.0f);
}

// dis[i] = (deg[i]+1)^-0.5, in place
__global__ __launch_bounds__(256) void k_dis(float* __restrict__ dd, int N) {
  int stride = gridDim.x * blockDim.x;
  for (int i = blockIdx.x * blockDim.x + threadIdx.x; i < N; i += stride)
    dd[i] = 1.0f / sqrtf(dd[i] + 1.0f);
}

// ---------------- GEMM: H = relu?(A) @ W (bf16 out); AGG = H*dis^2 + b ----
// One wave computes 4 rows x M cols. lane covers VEC=M/64 consecutive cols.
template <int K, int M, bool RELU>
__global__ __launch_bounds__(256) void k_gemm(const float* __restrict__ A,
                                              const float* __restrict__ W,
                                              const float* __restrict__ bias,
                                              const float* __restrict__ dis,
                                              unsigned short* __restrict__ H,
                                              float* __restrict__ AGG, int N) {
  constexpr int VEC = M / 64;
  const int lane = threadIdx.x & 63;
  const int wid = threadIdx.x >> 6;
  int row0 = (blockIdx.x * 4 + wid) * 4;
  row0 = __builtin_amdgcn_readfirstlane(row0);
  if (row0 >= N) return;
  const int cb = lane * VEC;

  float acc[4][VEC];
#pragma unroll
  for (int r = 0; r < 4; ++r)
#pragma unroll
    for (int v = 0; v < VEC; ++v) acc[r][v] = 0.f;

  int rr[4];
#pragma unroll
  for (int r = 0; r < 4; ++r) rr[r] = min(row0 + r, N - 1);

  for (int k = 0; k < K; k += 4) {
    float4 a4[4];
#pragma unroll
    for (int r = 0; r < 4; ++r)
      a4[r] = *(const float4*)&A[(size_t)rr[r] * K + k];
#pragma unroll
    for (int kk = 0; kk < 4; ++kk) {
      float w[VEC];
      const float* wp = &W[(size_t)(k + kk) * M + cb];
      if (VEC == 4) {
        float4 t = *(const float4*)wp;
        w[0] = t.x; w[1] = t.y; w[2] = t.z; w[3] = t.w;
      } else if (VEC == 2) {
        float2 t = *(const float2*)wp;
        w[0] = t.x; w[1] = t.y;
      } else {
        w[0] = *wp;
      }
#pragma unroll
      for (int r = 0; r < 4; ++r) {
        float a = (&a4[r].x)[kk];
        if (RELU) a = fmaxf(a, 0.f);
#pragma unroll
        for (int v = 0; v < VEC; ++v) acc[r][v] = fmaf(a, w[v], acc[r][v]);
      }
    }
  }

  float b[VEC];
#pragma unroll
  for (int v = 0; v < VEC; ++v) b[v] = bias[cb + v];

#pragma unroll
  for (int r = 0; r < 4; ++r) {
    int row = row0 + r;
    if (row >= N) break;
    float dv = dis[row];
    float sc = dv * dv;
    float av[VEC];
    unsigned short hb[VEC];
#pragma unroll
    for (int v = 0; v < VEC; ++v) {
      av[v] = fmaf(acc[r][v], sc, b[v]);
      hb[v] = f2bf(acc[r][v]);
    }
    unsigned short* Hp = &H[(size_t)row * M + cb];
    float* Ap = &AGG[(size_t)row * M + cb];
    if (VEC == 4) {
      *(ushort4*)Hp = make_ushort4(hb[0], hb[1], hb[2], hb[3]);
      *(float4*)Ap = make_float4(av[0], av[1], av[2], av[3]);
    } else if (VEC == 2) {
      *(ushort2*)Hp = make_ushort2(hb[0], hb[1]);
      *(float2*)Ap = make_float2(av[0], av[1]);
    } else {
      *Hp = hb[0];
      *Ap = av[0];
    }
  }
}

// ---------------- edge scatter: AGG[dst] += H[src] * dis[src]*dis[dst] ----
template <int M>
__global__ __launch_bounds__(256) void k_scat(const int* __restrict__ ei,
                                              const float* __restrict__ dis,
                                              const unsigned short* __restrict__ H,
                                              float* __restrict__ AGG, int E) {
  constexpr int VEC = M / 64;
  const int lane = threadIdx.x & 63;
  int gw = (blockIdx.x * blockDim.x + threadIdx.x) >> 6;
  gw = __builtin_amdgcn_readfirstlane(gw);
  const int nw = (gridDim.x * blockDim.x) >> 6;
  for (int e = gw; e < E; e += nw) {
    const int s = ei[e];
    const int d = ei[E + e];
    const float ne = dis[s] * dis[d];
    const unsigned short* hp = &H[(size_t)s * M + lane * VEC];
    float* ap = &AGG[(size_t)d * M + lane * VEC];
    if (VEC == 4) {
      ushort4 h4 = *(const ushort4*)hp;
      atomicAdd(&ap[0], bf2f(h4.x) * ne);
      atomicAdd(&ap[1], bf2f(h4.y) * ne);
      atomicAdd(&ap[2], bf2f(h4.z) * ne);
      atomicAdd(&ap[3], bf2f(h4.w) * ne);
    } else if (VEC == 2) {
      ushort2 h2 = *(const ushort2*)hp;
      atomicAdd(&ap[0], bf2f(h2.x) * ne);
      atomicAdd(&ap[1], bf2f(h2.y) * ne);
    } else {
      atomicAdd(&ap[0], bf2f(hp[0]) * ne);
    }
  }
}

// ---------------- pooling: pooled[g][c] += relu(A3[r][c]); counts ---------
__global__ __launch_bounds__(256) void k_pool(const float* __restrict__ A3,
                                              const int* __restrict__ batch,
                                              float* __restrict__ pooled,
                                              float* __restrict__ counts,
                                              int N) {
  const int c = threadIdx.x;  // 256 cols
  const int chunk = (N + gridDim.x - 1) / gridDim.x;
  const int r0 = blockIdx.x * chunk;
  const int r1 = min(N, r0 + chunk);
  if (r0 >= r1) return;
  int cur = batch[r0];
  float acc = 0.f;
  int runlen = 0;
  for (int r = r0; r < r1; ++r) {
    int g = batch[r];
    if (g != cur) {
      atomicAdd(&pooled[cur * 256 + c], acc);
      if (c == 0) atomicAdd(&counts[cur], (float)runlen);
      acc = 0.f;
      runlen = 0;
      cur = g;
    }
    acc += fmaxf(A3[(size_t)r * 256 + c], 0.f);
    runlen++;
  }
  atomicAdd(&pooled[cur * 256 + c], acc);
  if (c == 0) atomicAdd(&counts[cur], (float)runlen);
}

// ---------------- final FC: out[g] = pooled[g]/cnt . Wfc + bfc ------------
__global__ __launch_bounds__(256) void k_final(const float* __restrict__ pooled,
                                               const float* __restrict__ counts,
                                               const float* __restrict__ Wfc,
                                               const float* __restrict__ bfc,
                                               float* __restrict__ out) {
  __shared__ float red[4];
  const int t = threadIdx.x;
  for (int g = 0; g < 8; ++g) {
    float v = pooled[g * 256 + t] / counts[g] * Wfc[t];
#pragma unroll
    for (int off = 32; off > 0; off >>= 1) v += __shfl_down(v, off, 64);
    if ((t & 63) == 0) red[t >> 6] = v;
    __syncthreads();
    if (t == 0) out[g] = red[0] + red[1] + red[2] + red[3] + bfc[0];
    __syncthreads();
  }
}

extern "C" void kernel_launch(void* const* d_in, const int* in_sizes, int n_in,
                              void* d_out, int out_size, void* d_ws,
                              size_t ws_size, hipStream_t stream) {
  const float* x = (const float*)d_in[0];
  const int* ei = (const int*)d_in[1];
  const int* batch = (const int*)d_in[2];
  const float* W1 = (const float*)d_in[3];
  const float* b1 = (const float*)d_in[4];
  const float* W2 = (const float*)d_in[5];
  const float* b2 = (const float*)d_in[6];
  const float* W3 = (const float*)d_in[7];
  const float* b3 = (const float*)d_in[8];
  const float* Wfc = (const float*)d_in[9];
  const float* bfc = (const float*)d_in[10];
  float* out = (float*)d_out;

  const int N = in_sizes[0] / 128;
  const int E = in_sizes[1] / 2;

  // workspace layout (fp32 slots); H is bf16 occupying N*128 fp32 slots
  float* ws = (float*)d_ws;
  size_t o_dis = 0;
  size_t o_counts = (size_t)N;
  size_t o_pooled = (size_t)N + 8;
  size_t o_h = (((size_t)N + 8 + 2048) + 63) & ~(size_t)63;
  size_t o_a1 = o_h + (size_t)N * 128;   // H: N*256 bf16 = N*128 f32 slots
  size_t o_a2 = o_a1 + (size_t)N * 64;
  size_t o_a3 = o_a2 + (size_t)N * 128;
  // total: o_a3 + N*256 floats ~= N*577*4B ~= 230.8 MB for N=100000

  float* dis = ws + o_dis;
  float* counts = ws + o_counts;
  float* pooled = ws + o_pooled;
  unsigned short* H = (unsigned short*)(ws + o_h);
  float* A1 = ws + o_a1;
  float* A2 = ws + o_a2;
  float* A3 = ws + o_a3;

  hipMemsetAsync(dis, 0, (size_t)N * sizeof(float), stream);
  hipMemsetAsync(counts, 0, (8 + 2048) * sizeof(float), stream);

  k_deg<<<2048, 256, 0, stream>>>(ei, dis, E);
  k_dis<<<(N + 255) / 256, 256, 0, stream>>>(dis, N);

  const int gblocks = (N + 15) / 16;
  k_gemm<128, 64, false><<<gblocks, 256, 0, stream>>>(x, W1, b1, dis, H, A1, N);
  k_scat<64><<<2048, 256, 0, stream>>>(ei, dis, H, A1, E);
  k_gemm<64, 128, true><<<gblocks, 256, 0, stream>>>(A1, W2, b2, dis, H, A2, N);
  k_scat<128><<<2048, 256, 0, stream>>>(ei, dis, H, A2, E);
  k_gemm<128, 256, true><<<gblocks, 256, 0, stream>>>(A2, W3, b3, dis, H, A3, N);
  k_scat<256><<<2048, 256, 0, stream>>>(ei, dis, H, A3, E);

  k_pool<<<512, 256, 0, stream>>>(A3, batch, pooled, counts, N);
  k_final<<<1, 256, 0, stream>>>(pooled, counts, Wfc, bfc, out);
}

// Round 3
// 725.921 us; speedup vs baseline: 5.5109x; 5.5109x over previous
//
#include <hip/hip_runtime.h>
#include <hip/hip_bf16.h>

static __device__ __forceinline__ unsigned short f2bf(float f) {
  __hip_bfloat16 b = __float2bfloat16(f);  // round-to-nearest-even
  return *reinterpret_cast<unsigned short*>(&b);
}
static __device__ __forceinline__ float bf2f(unsigned short u) {
  unsigned int x = ((unsigned int)u) << 16;
  return __builtin_bit_cast(float, x);
}

// ---------------- in-degree histogram over dst ----------------------------
__global__ __launch_bounds__(256) void k_hist(const int* __restrict__ ei,
                                              int* __restrict__ cnt, int E) {
  int stride = gridDim.x * blockDim.x;
  for (int i = blockIdx.x * blockDim.x + threadIdx.x; i < E; i += stride)
    atomicAdd(&cnt[ei[E + i]], 1);
}

// dis[i] = (cnt[i]+1)^-0.5
__global__ __launch_bounds__(256) void k_dis(const int* __restrict__ cnt,
                                             float* __restrict__ dis, int N) {
  int stride = gridDim.x * blockDim.x;
  for (int i = blockIdx.x * blockDim.x + threadIdx.x; i < N; i += stride)
    dis[i] = 1.0f / sqrtf((float)cnt[i] + 1.0f);
}

// ---------------- exclusive scan of cnt -> row_ptr (3 small kernels) ------
__global__ __launch_bounds__(256) void k_scan1(const int* __restrict__ cnt,
                                               int* __restrict__ row_tmp,
                                               int* __restrict__ bsum, int N) {
  __shared__ int sd[256];
  const int tid = threadIdx.x;
  const int i = blockIdx.x * 256 + tid;
  int v = (i < N) ? cnt[i] : 0;
  sd[tid] = v;
  __syncthreads();
#pragma unroll
  for (int off = 1; off < 256; off <<= 1) {
    int t = (tid >= off) ? sd[tid - off] : 0;
    __syncthreads();
    sd[tid] += t;
    __syncthreads();
  }
  if (i < N) row_tmp[i] = sd[tid] - v;  // exclusive
  if (tid == 255) bsum[blockIdx.x] = sd[255];
}

__global__ __launch_bounds__(1024) void k_scan2(int* __restrict__ bsum, int nb) {
  __shared__ int sd[1024];
  const int t = threadIdx.x;
  int v = (t < nb) ? bsum[t] : 0;
  sd[t] = v;
  __syncthreads();
#pragma unroll
  for (int off = 1; off < 1024; off <<= 1) {
    int x = (t >= off) ? sd[t - off] : 0;
    __syncthreads();
    sd[t] += x;
    __syncthreads();
  }
  if (t < nb) bsum[t] = sd[t] - v;  // exclusive
}

__global__ __launch_bounds__(256) void k_scan3(const int* __restrict__ row_tmp,
                                               const int* __restrict__ bsum,
                                               int* __restrict__ row_ptr,
                                               int* __restrict__ cursor, int N,
                                               int E) {
  const int i = blockIdx.x * 256 + threadIdx.x;
  if (i < N) {
    int rp = row_tmp[i] + bsum[i >> 8];
    row_ptr[i] = rp;
    cursor[i] = rp;
  }
  if (i == 0) row_ptr[N] = E;
}

// ---------------- CSR fill: col[pos] = src, bucketed by dst ---------------
__global__ __launch_bounds__(256) void k_fill(const int* __restrict__ ei,
                                              int* __restrict__ cursor,
                                              int* __restrict__ col, int E) {
  int stride = gridDim.x * blockDim.x;
  for (int e = blockIdx.x * blockDim.x + threadIdx.x; e < E; e += stride) {
    int s = ei[e];
    int d = ei[E + e];
    int pos = atomicAdd(&cursor[d], 1);
    col[pos] = s;
  }
}

// ---------------- GEMM: H = relu?(A) @ W  (bf16 out) ----------------------
// One wave computes 4 rows x M cols. lane covers VEC=M/64 consecutive cols.
template <int K, int M, bool RELU>
__global__ __launch_bounds__(256) void k_gemm(const float* __restrict__ A,
                                              const float* __restrict__ W,
                                              unsigned short* __restrict__ H,
                                              int N) {
  constexpr int VEC = M / 64;
  const int lane = threadIdx.x & 63;
  const int wid = threadIdx.x >> 6;
  int row0 = (blockIdx.x * 4 + wid) * 4;
  row0 = __builtin_amdgcn_readfirstlane(row0);
  if (row0 >= N) return;
  const int cb = lane * VEC;

  float acc[4][VEC];
#pragma unroll
  for (int r = 0; r < 4; ++r)
#pragma unroll
    for (int v = 0; v < VEC; ++v) acc[r][v] = 0.f;

  int rr[4];
#pragma unroll
  for (int r = 0; r < 4; ++r) rr[r] = min(row0 + r, N - 1);

  for (int k = 0; k < K; k += 4) {
    float4 a4[4];
#pragma unroll
    for (int r = 0; r < 4; ++r)
      a4[r] = *(const float4*)&A[(size_t)rr[r] * K + k];
#pragma unroll
    for (int kk = 0; kk < 4; ++kk) {
      float w[VEC];
      const float* wp = &W[(size_t)(k + kk) * M + cb];
      if (VEC == 4) {
        float4 t = *(const float4*)wp;
        w[0] = t.x; w[1] = t.y; w[2] = t.z; w[3] = t.w;
      } else if (VEC == 2) {
        float2 t = *(const float2*)wp;
        w[0] = t.x; w[1] = t.y;
      } else {
        w[0] = *wp;
      }
#pragma unroll
      for (int r = 0; r < 4; ++r) {
        float a = (&a4[r].x)[kk];
        if (RELU) a = fmaxf(a, 0.f);
#pragma unroll
        for (int v = 0; v < VEC; ++v) acc[r][v] = fmaf(a, w[v], acc[r][v]);
      }
    }
  }

#pragma unroll
  for (int r = 0; r < 4; ++r) {
    int row = row0 + r;
    if (row >= N) break;
    unsigned short hb[VEC];
#pragma unroll
    for (int v = 0; v < VEC; ++v) hb[v] = f2bf(acc[r][v]);
    unsigned short* Hp = &H[(size_t)row * M + cb];
    if (VEC == 4)
      *(ushort4*)Hp = make_ushort4(hb[0], hb[1], hb[2], hb[3]);
    else if (VEC == 2)
      *(ushort2*)Hp = make_ushort2(hb[0], hb[1]);
    else
      *Hp = hb[0];
  }
}

// ------- CSR aggregation: A[d] = b + H[d]*dis[d]^2 + sum H[s]*dis[s]*dis[d]
template <int M>
__global__ __launch_bounds__(256) void k_agg(const int* __restrict__ row_ptr,
                                             const int* __restrict__ col,
                                             const float* __restrict__ dis,
                                             const unsigned short* __restrict__ H,
                                             const float* __restrict__ bias,
                                             float* __restrict__ A, int N) {
  constexpr int VEC = M / 64;
  const int lane = threadIdx.x & 63;
  int d = blockIdx.x * 4 + (threadIdx.x >> 6);
  if (d >= N) return;
  const int cb = lane * VEC;
  const float disd = dis[d];

  float acc[VEC];
  {  // self-loop + bias
    const float sc = disd * disd;
    const unsigned short* hp = &H[(size_t)d * M + cb];
    if (VEC == 4) {
      ushort4 u = *(const ushort4*)hp;
      acc[0] = fmaf(bf2f(u.x), sc, bias[cb + 0]);
      acc[1] = fmaf(bf2f(u.y), sc, bias[cb + 1]);
      acc[2] = fmaf(bf2f(u.z), sc, bias[cb + 2]);
      acc[3] = fmaf(bf2f(u.w), sc, bias[cb + 3]);
    } else if (VEC == 2) {
      ushort2 u = *(const ushort2*)hp;
      acc[0] = fmaf(bf2f(u.x), sc, bias[cb + 0]);
      acc[1] = fmaf(bf2f(u.y), sc, bias[cb + 1]);
    } else {
      acc[0] = fmaf(bf2f(*hp), sc, bias[cb]);
    }
  }

  const int beg = row_ptr[d];
  const int end = row_ptr[d + 1];
  int s_next = (beg < end) ? col[beg] : 0;
  for (int j = beg; j < end; ++j) {
    const int s = s_next;
    if (j + 1 < end) s_next = col[j + 1];
    const float ne = dis[s] * disd;
    const unsigned short* hp = &H[(size_t)s * M + cb];
    if (VEC == 4) {
      ushort4 u = *(const ushort4*)hp;
      acc[0] = fmaf(bf2f(u.x), ne, acc[0]);
      acc[1] = fmaf(bf2f(u.y), ne, acc[1]);
      acc[2] = fmaf(bf2f(u.z), ne, acc[2]);
      acc[3] = fmaf(bf2f(u.w), ne, acc[3]);
    } else if (VEC == 2) {
      ushort2 u = *(const ushort2*)hp;
      acc[0] = fmaf(bf2f(u.x), ne, acc[0]);
      acc[1] = fmaf(bf2f(u.y), ne, acc[1]);
    } else {
      acc[0] = fmaf(bf2f(*hp), ne, acc[0]);
    }
  }

  float* ap = &A[(size_t)d * M + cb];
  if (VEC == 4)
    *(float4*)ap = make_float4(acc[0], acc[1], acc[2], acc[3]);
  else if (VEC == 2)
    *(float2*)ap = make_float2(acc[0], acc[1]);
  else
    *ap = acc[0];
}

// ---------------- pooling: pooled[g][c] += relu(A3[r][c]); counts ---------
__global__ __launch_bounds__(256) void k_pool(const float* __restrict__ A3,
                                              const int* __restrict__ batch,
                                              float* __restrict__ pooled,
                                              float* __restrict__ counts,
                                              int N) {
  const int c = threadIdx.x;  // 256 cols
  const int chunk = (N + gridDim.x - 1) / gridDim.x;
  const int r0 = blockIdx.x * chunk;
  const int r1 = min(N, r0 + chunk);
  if (r0 >= r1) return;
  int cur = batch[r0];
  float acc = 0.f;
  int runlen = 0;
  for (int r = r0; r < r1; ++r) {
    int g = batch[r];
    if (g != cur) {
      atomicAdd(&pooled[cur * 256 + c], acc);
      if (c == 0) atomicAdd(&counts[cur], (float)runlen);
      acc = 0.f;
      runlen = 0;
      cur = g;
    }
    acc += fmaxf(A3[(size_t)r * 256 + c], 0.f);
    runlen++;
  }
  atomicAdd(&pooled[cur * 256 + c], acc);
  if (c == 0) atomicAdd(&counts[cur], (float)runlen);
}

// ---------------- final FC: out[g] = pooled[g]/cnt . Wfc + bfc ------------
__global__ __launch_bounds__(256) void k_final(const float* __restrict__ pooled,
                                               const float* __restrict__ counts,
                                               const float* __restrict__ Wfc,
                                               const float* __restrict__ bfc,
                                               float* __restrict__ out) {
  __shared__ float red[4];
  const int t = threadIdx.x;
  for (int g = 0; g < 8; ++g) {
    float v = pooled[g * 256 + t] / counts[g] * Wfc[t];
#pragma unroll
    for (int off = 32; off > 0; off >>= 1) v += __shfl_down(v, off, 64);
    if ((t & 63) == 0) red[t >> 6] = v;
    __syncthreads();
    if (t == 0) out[g] = red[0] + red[1] + red[2] + red[3] + bfc[0];
    __syncthreads();
  }
}

extern "C" void kernel_launch(void* const* d_in, const int* in_sizes, int n_in,
                              void* d_out, int out_size, void* d_ws,
                              size_t ws_size, hipStream_t stream) {
  const float* x = (const float*)d_in[0];
  const int* ei = (const int*)d_in[1];
  const int* batch = (const int*)d_in[2];
  const float* W1 = (const float*)d_in[3];
  const float* b1 = (const float*)d_in[4];
  const float* W2 = (const float*)d_in[5];
  const float* b2 = (const float*)d_in[6];
  const float* W3 = (const float*)d_in[7];
  const float* b3 = (const float*)d_in[8];
  const float* Wfc = (const float*)d_in[9];
  const float* bfc = (const float*)d_in[10];
  float* out = (float*)d_out;

  const int N = in_sizes[0] / 128;
  const int E = in_sizes[1] / 2;
  const int nb = (N + 255) / 256;

  // -------- workspace layout (4-byte units) --------
  float* ws = (float*)d_ws;
  size_t o = 0;
  float* dis = ws + o;            o += (size_t)N;
  int* cnt = (int*)(ws + o);      o += (size_t)N;
  int* row_tmp = (int*)(ws + o);  o += (size_t)N;
  int* bsum = (int*)(ws + o);     o += 1024;
  int* row_ptr = (int*)(ws + o);  o += (size_t)N + 1;
  int* cursor = (int*)(ws + o);   o += (size_t)N;
  int* col = (int*)(ws + o);      o += (size_t)E;
  float* pooled = ws + o;         o += 2048;
  float* counts = ws + o;         o += 16;
  o = (o + 63) & ~(size_t)63;
  unsigned short* H = (unsigned short*)(ws + o);  o += (size_t)N * 128;  // N*256 bf16
  float* A1 = ws + o;             // region reused: A3 aliases A1/A2
  float* A2 = ws + o + (size_t)N * 64;
  float* A3 = ws + o;             o += (size_t)N * 256;
  // total ~ N*389 + E + 3k floats  ~= 159 MB for N=1e5, E=8e5

  hipMemsetAsync(cnt, 0, (size_t)N * sizeof(int), stream);
  hipMemsetAsync(pooled, 0, (2048 + 16) * sizeof(float), stream);

  k_hist<<<2048, 256, 0, stream>>>(ei, cnt, E);
  k_dis<<<nb, 256, 0, stream>>>(cnt, dis, N);
  k_scan1<<<nb, 256, 0, stream>>>(cnt, row_tmp, bsum, N);
  k_scan2<<<1, 1024, 0, stream>>>(bsum, nb);
  k_scan3<<<nb, 256, 0, stream>>>(row_tmp, bsum, row_ptr, cursor, N, E);
  k_fill<<<2048, 256, 0, stream>>>(ei, cursor, col, E);

  const int gblocks = (N + 15) / 16;
  const int ablocks = (N + 3) / 4;
  k_gemm<128, 64, false><<<gblocks, 256, 0, stream>>>(x, W1, H, N);
  k_agg<64><<<ablocks, 256, 0, stream>>>(row_ptr, col, dis, H, b1, A1, N);
  k_gemm<64, 128, true><<<gblocks, 256, 0, stream>>>(A1, W2, H, N);
  k_agg<128><<<ablocks, 256, 0, stream>>>(row_ptr, col, dis, H, b2, A2, N);
  k_gemm<128, 256, true><<<gblocks, 256, 0, stream>>>(A2, W3, H, N);
  k_agg<256><<<ablocks, 256, 0, stream>>>(row_ptr, col, dis, H, b3, A3, N);

  k_pool<<<512, 256, 0, stream>>>(A3, batch, pooled, counts, N);
  k_final<<<1, 256, 0, stream>>>(pooled, counts, Wfc, bfc, out);
}

// Round 4
// 541.668 us; speedup vs baseline: 7.3855x; 1.3402x over previous
//
#include <hip/hip_runtime.h>
#include <hip/hip_bf16.h>

typedef __attribute__((ext_vector_type(8))) short short8v;   // 8 bf16 (4 VGPR)
typedef __attribute__((ext_vector_type(4))) float f32x4;

static __device__ __forceinline__ unsigned short f2bf(float f) {
  __hip_bfloat16 b = __float2bfloat16(f);  // round-to-nearest-even
  return *reinterpret_cast<unsigned short*>(&b);
}
static __device__ __forceinline__ float bf2f(unsigned short u) {
  unsigned int x = ((unsigned int)u) << 16;
  return __builtin_bit_cast(float, x);
}

// ---------------- in-degree histogram over dst ----------------------------
__global__ __launch_bounds__(256) void k_hist(const int* __restrict__ ei,
                                              int* __restrict__ cnt, int E) {
  int stride = gridDim.x * blockDim.x;
  for (int i = blockIdx.x * blockDim.x + threadIdx.x; i < E; i += stride)
    atomicAdd(&cnt[ei[E + i]], 1);
}

// dis[i] = (cnt[i]+1)^-0.5
__global__ __launch_bounds__(256) void k_dis(const int* __restrict__ cnt,
                                             float* __restrict__ dis, int N) {
  int stride = gridDim.x * blockDim.x;
  for (int i = blockIdx.x * blockDim.x + threadIdx.x; i < N; i += stride)
    dis[i] = 1.0f / sqrtf((float)cnt[i] + 1.0f);
}

// ---------------- exclusive scan of cnt -> row_ptr ------------------------
__global__ __launch_bounds__(256) void k_scan1(const int* __restrict__ cnt,
                                               int* __restrict__ row_tmp,
                                               int* __restrict__ bsum, int N) {
  __shared__ int sd[256];
  const int tid = threadIdx.x;
  const int i = blockIdx.x * 256 + tid;
  int v = (i < N) ? cnt[i] : 0;
  sd[tid] = v;
  __syncthreads();
#pragma unroll
  for (int off = 1; off < 256; off <<= 1) {
    int t = (tid >= off) ? sd[tid - off] : 0;
    __syncthreads();
    sd[tid] += t;
    __syncthreads();
  }
  if (i < N) row_tmp[i] = sd[tid] - v;  // exclusive
  if (tid == 255) bsum[blockIdx.x] = sd[255];
}

__global__ __launch_bounds__(1024) void k_scan2(int* __restrict__ bsum, int nb) {
  __shared__ int sd[1024];
  const int t = threadIdx.x;
  int v = (t < nb) ? bsum[t] : 0;
  sd[t] = v;
  __syncthreads();
#pragma unroll
  for (int off = 1; off < 1024; off <<= 1) {
    int x = (t >= off) ? sd[t - off] : 0;
    __syncthreads();
    sd[t] += x;
    __syncthreads();
  }
  if (t < nb) bsum[t] = sd[t] - v;  // exclusive
}

__global__ __launch_bounds__(256) void k_scan3(const int* __restrict__ row_tmp,
                                               const int* __restrict__ bsum,
                                               int* __restrict__ row_ptr,
                                               int* __restrict__ cursor, int N,
                                               int E) {
  const int i = blockIdx.x * 256 + threadIdx.x;
  if (i < N) {
    int rp = row_tmp[i] + bsum[i >> 8];
    row_ptr[i] = rp;
    cursor[i] = rp;
  }
  if (i == 0) row_ptr[N] = E;
}

// ---------------- CSR fill: col[pos] = src, bucketed by dst ---------------
__global__ __launch_bounds__(256) void k_fill(const int* __restrict__ ei,
                                              int* __restrict__ cursor,
                                              int* __restrict__ col, int E) {
  int stride = gridDim.x * blockDim.x;
  for (int e = blockIdx.x * blockDim.x + threadIdx.x; e < E; e += stride) {
    int s = ei[e];
    int d = ei[E + e];
    int pos = atomicAdd(&cursor[d], 1);
    col[pos] = s;
  }
}

// ---------------- x (fp32) -> bf16 ----------------------------------------
__global__ __launch_bounds__(256) void k_xb(const float* __restrict__ x,
                                            unsigned short* __restrict__ xb,
                                            long long n4) {
  long long stride = (long long)gridDim.x * blockDim.x;
  for (long long i = blockIdx.x * (long long)blockDim.x + threadIdx.x; i < n4;
       i += stride) {
    float4 v = *(const float4*)&x[i * 4];
    *(ushort4*)&xb[i * 4] =
        make_ushort4(f2bf(v.x), f2bf(v.y), f2bf(v.z), f2bf(v.w));
  }
}

// ---------------- pack W (KxM fp32) into B-fragment layout ----------------
// frag t = (ct*KT + kt)*64 + lane ; lane holds W[kt*32+(lane>>4)*8+j][ct*16+(lane&15)]
__global__ __launch_bounds__(256) void k_pack(const float* __restrict__ W,
                                              unsigned short* __restrict__ Wp,
                                              int K, int M) {
  int t = blockIdx.x * 256 + threadIdx.x;
  int KT = K >> 5;
  int total = (M >> 4) * KT * 64;
  if (t >= total) return;
  int lane = t & 63;
  int tile = t >> 6;
  int kt = tile % KT;
  int ct = tile / KT;
  int c = ct * 16 + (lane & 15);
  int k0 = kt * 32 + (lane >> 4) * 8;
  unsigned short v[8];
#pragma unroll
  for (int j = 0; j < 8; ++j) v[j] = f2bf(W[(size_t)(k0 + j) * M + c]);
  ushort4* dst = (ushort4*)&Wp[(size_t)t * 8];
  dst[0] = make_ushort4(v[0], v[1], v[2], v[3]);
  dst[1] = make_ushort4(v[4], v[5], v[6], v[7]);
}

// ------- CSR aggregation (bf16 in/out): P[d] = Hin[d]*dis_d^2 + sum Hin[s]*dis_s*dis_d
template <int M>
__global__ __launch_bounds__(256) void k_agg(const int* __restrict__ row_ptr,
                                             const int* __restrict__ col,
                                             const float* __restrict__ dis,
                                             const unsigned short* __restrict__ Hin,
                                             unsigned short* __restrict__ Pout,
                                             int N) {
  constexpr int VEC = M / 64;
  const int lane = threadIdx.x & 63;
  int d = blockIdx.x * 4 + (threadIdx.x >> 6);
  if (d >= N) return;
  const int cb = lane * VEC;
  const float disd = dis[d];

  float acc[VEC];
  {  // self-loop term
    const float sc = disd * disd;
    const unsigned short* hp = &Hin[(size_t)d * M + cb];
    if (VEC == 2) {
      ushort2 u = *(const ushort2*)hp;
      acc[0] = bf2f(u.x) * sc;
      acc[1] = bf2f(u.y) * sc;
    } else {
      acc[0] = bf2f(*hp) * sc;
    }
  }

  const int beg = row_ptr[d];
  const int end = row_ptr[d + 1];
  int s_next = (beg < end) ? col[beg] : 0;
  for (int j = beg; j < end; ++j) {
    const int s = s_next;
    if (j + 1 < end) s_next = col[j + 1];
    const float ne = dis[s] * disd;
    const unsigned short* hp = &Hin[(size_t)s * M + cb];
    if (VEC == 2) {
      ushort2 u = *(const ushort2*)hp;
      acc[0] = fmaf(bf2f(u.x), ne, acc[0]);
      acc[1] = fmaf(bf2f(u.y), ne, acc[1]);
    } else {
      acc[0] = fmaf(bf2f(*hp), ne, acc[0]);
    }
  }

  unsigned short* pp = &Pout[(size_t)d * M + cb];
  if (VEC == 2)
    *(ushort2*)pp = make_ushort2(f2bf(acc[0]), f2bf(acc[1]));
  else
    *pp = f2bf(acc[0]);
}

// ---------------- MFMA GEMM: Hout = relu(A @ W + b), bf16 in/out ----------
// wave handles 16 rows x M cols via mfma_f32_16x16x32_bf16.
// A frag: lane holds A[row0+(lane&15)][kt*32+(lane>>4)*8 + 0..7]
// D frag: row=(lane>>4)*4+reg, col=lane&15  (verified layout, guide §3)
template <int K, int M>
__global__ __launch_bounds__(256) void k_mm(const unsigned short* __restrict__ A,
                                            const unsigned short* __restrict__ Wp,
                                            const float* __restrict__ bias,
                                            unsigned short* __restrict__ Hout,
                                            int N) {
  constexpr int KT = K / 32, CT = M / 16;
  const int lane = threadIdx.x & 63;
  const int wid = threadIdx.x >> 6;
  int row0 = (blockIdx.x * 4 + wid) * 16;
  row0 = __builtin_amdgcn_readfirstlane(row0);
  if (row0 >= N) return;
  const int r = lane & 15;
  const int kh = lane >> 4;

  int arow = row0 + r;
  if (arow >= N) arow = N - 1;

  f32x4 acc[CT];
#pragma unroll
  for (int ct = 0; ct < CT; ++ct) acc[ct] = (f32x4){0.f, 0.f, 0.f, 0.f};

#pragma unroll
  for (int kt = 0; kt < KT; ++kt) {
    short8v a = *(const short8v*)&A[(size_t)arow * K + kt * 32 + kh * 8];
#pragma unroll
    for (int ct = 0; ct < CT; ++ct) {
      short8v b = *(const short8v*)&Wp[(size_t)((ct * KT + kt) * 64 + lane) * 8];
      acc[ct] = __builtin_amdgcn_mfma_f32_16x16x32_bf16(a, b, acc[ct], 0, 0, 0);
    }
  }

  const int orow0 = row0 + kh * 4;
#pragma unroll
  for (int ct = 0; ct < CT; ++ct) {
    const int c = ct * 16 + r;
    const float bv = bias[c];
#pragma unroll
    for (int reg = 0; reg < 4; ++reg) {
      int row = orow0 + reg;
      if (row < N) {
        float v = fmaxf(acc[ct][reg] + bv, 0.f);
        Hout[(size_t)row * M + c] = f2bf(v);
      }
    }
  }
}

// ---------------- pooling (bf16 in, relu pre-applied) ---------------------
__global__ __launch_bounds__(256) void k_pool(const unsigned short* __restrict__ H4,
                                              const int* __restrict__ batch,
                                              float* __restrict__ pooled,
                                              float* __restrict__ counts,
                                              int N) {
  const int c = threadIdx.x;  // 256 cols
  const int chunk = (N + gridDim.x - 1) / gridDim.x;
  const int r0 = blockIdx.x * chunk;
  const int r1 = min(N, r0 + chunk);
  if (r0 >= r1) return;
  int cur = batch[r0];
  float acc = 0.f;
  int runlen = 0;
  for (int r = r0; r < r1; ++r) {
    int g = batch[r];
    if (g != cur) {
      atomicAdd(&pooled[cur * 256 + c], acc);
      if (c == 0) atomicAdd(&counts[cur], (float)runlen);
      acc = 0.f;
      runlen = 0;
      cur = g;
    }
    acc += bf2f(H4[(size_t)r * 256 + c]);
    runlen++;
  }
  atomicAdd(&pooled[cur * 256 + c], acc);
  if (c == 0) atomicAdd(&counts[cur], (float)runlen);
}

// ---------------- final FC: out[g] = pooled[g]/cnt . Wfc + bfc ------------
__global__ __launch_bounds__(256) void k_final(const float* __restrict__ pooled,
                                               const float* __restrict__ counts,
                                               const float* __restrict__ Wfc,
                                               const float* __restrict__ bfc,
                                               float* __restrict__ out) {
  __shared__ float red[4];
  const int t = threadIdx.x;
  for (int g = 0; g < 8; ++g) {
    float v = pooled[g * 256 + t] / counts[g] * Wfc[t];
#pragma unroll
    for (int off = 32; off > 0; off >>= 1) v += __shfl_down(v, off, 64);
    if ((t & 63) == 0) red[t >> 6] = v;
    __syncthreads();
    if (t == 0) out[g] = red[0] + red[1] + red[2] + red[3] + bfc[0];
    __syncthreads();
  }
}

extern "C" void kernel_launch(void* const* d_in, const int* in_sizes, int n_in,
                              void* d_out, int out_size, void* d_ws,
                              size_t ws_size, hipStream_t stream) {
  const float* x = (const float*)d_in[0];
  const int* ei = (const int*)d_in[1];
  const int* batch = (const int*)d_in[2];
  const float* W1 = (const float*)d_in[3];
  const float* b1 = (const float*)d_in[4];
  const float* W2 = (const float*)d_in[5];
  const float* b2 = (const float*)d_in[6];
  const float* W3 = (const float*)d_in[7];
  const float* b3 = (const float*)d_in[8];
  const float* Wfc = (const float*)d_in[9];
  const float* bfc = (const float*)d_in[10];
  float* out = (float*)d_out;

  const int N = in_sizes[0] / 128;
  const int E = in_sizes[1] / 2;
  const int nb = (N + 255) / 256;

  // -------- workspace layout (4-byte units), ~108 MB total --------
  float* ws = (float*)d_ws;
  size_t o = 0;
  float* dis = ws + o;            o += (size_t)N;
  int* cnt = (int*)(ws + o);      o += (size_t)N;
  int* row_tmp = (int*)(ws + o);  o += (size_t)N;
  int* bsum = (int*)(ws + o);     o += 1024;
  int* row_ptr = (int*)(ws + o);  o += (size_t)N + 1;
  int* cursor = (int*)(ws + o);   o += (size_t)N;
  int* col = (int*)(ws + o);      o += (size_t)E;
  float* pooled = ws + o;         o += 2048;
  float* counts = ws + o;         o += 16;
  unsigned short* Wp1 = (unsigned short*)(ws + o); o += 4096;   // 128x64 bf16
  unsigned short* Wp2 = (unsigned short*)(ws + o); o += 4096;   // 64x128
  unsigned short* Wp3 = (unsigned short*)(ws + o); o += 16384;  // 128x256
  o = (o + 63) & ~(size_t)63;
  unsigned short* bufA = (unsigned short*)(ws + o); o += (size_t)N * 64;   // Xb/h2/h3 (<=128ch)
  unsigned short* bufB = (unsigned short*)(ws + o); o += (size_t)N * 64;   // P1/P2/P3 (<=128ch)
  unsigned short* bufC = (unsigned short*)(ws + o); o += (size_t)N * 128;  // h4 (256ch)

  hipMemsetAsync(cnt, 0, (size_t)N * sizeof(int), stream);
  hipMemsetAsync(pooled, 0, (2048 + 16) * sizeof(float), stream);

  k_hist<<<2048, 256, 0, stream>>>(ei, cnt, E);
  k_dis<<<nb, 256, 0, stream>>>(cnt, dis, N);
  k_scan1<<<nb, 256, 0, stream>>>(cnt, row_tmp, bsum, N);
  k_scan2<<<1, 1024, 0, stream>>>(bsum, nb);
  k_scan3<<<nb, 256, 0, stream>>>(row_tmp, bsum, row_ptr, cursor, N, E);
  k_fill<<<2048, 256, 0, stream>>>(ei, cursor, col, E);

  k_xb<<<2048, 256, 0, stream>>>(x, bufA, (long long)N * 32);
  k_pack<<<(128 * 64 / 8 + 255) / 256, 256, 0, stream>>>(W1, Wp1, 128, 64);
  k_pack<<<(64 * 128 / 8 + 255) / 256, 256, 0, stream>>>(W2, Wp2, 64, 128);
  k_pack<<<(128 * 256 / 8 + 255) / 256, 256, 0, stream>>>(W3, Wp3, 128, 256);

  const int ablocks = (N + 3) / 4;
  const int mblocks = (N + 63) / 64;
  // L1: P1 = agg(xb) [128ch]; h2 = relu(P1 W1 + b1) [64ch]
  k_agg<128><<<ablocks, 256, 0, stream>>>(row_ptr, col, dis, bufA, bufB, N);
  k_mm<128, 64><<<mblocks, 256, 0, stream>>>(bufB, Wp1, b1, bufA, N);
  // L2: P2 = agg(h2) [64ch]; h3 = relu(P2 W2 + b2) [128ch]
  k_agg<64><<<ablocks, 256, 0, stream>>>(row_ptr, col, dis, bufA, bufB, N);
  k_mm<64, 128><<<mblocks, 256, 0, stream>>>(bufB, Wp2, b2, bufA, N);
  // L3: P3 = agg(h3) [128ch]; h4 = relu(P3 W3 + b3) [256ch]
  k_agg<128><<<ablocks, 256, 0, stream>>>(row_ptr, col, dis, bufA, bufB, N);
  k_mm<128, 256><<<mblocks, 256, 0, stream>>>(bufB, Wp3, b3, bufC, N);

  k_pool<<<512, 256, 0, stream>>>(bufC, batch, pooled, counts, N);
  k_final<<<1, 256, 0, stream>>>(pooled, counts, Wfc, bfc, out);
}

// Round 5
// 457.371 us; speedup vs baseline: 8.7467x; 1.1843x over previous
//
#include <hip/hip_runtime.h>
#include <hip/hip_bf16.h>

typedef __attribute__((ext_vector_type(8))) short short8v;   // 8 bf16 (4 VGPR)
typedef __attribute__((ext_vector_type(4))) float f32x4;

static __device__ __forceinline__ unsigned short f2bf(float f) {
  __hip_bfloat16 b = __float2bfloat16(f);  // round-to-nearest-even
  return *reinterpret_cast<unsigned short*>(&b);
}
static __device__ __forceinline__ float bf2f(unsigned short u) {
  unsigned int x = ((unsigned int)u) << 16;
  return __builtin_bit_cast(float, x);
}
static __device__ __forceinline__ float bflo(unsigned int u) {
  return __builtin_bit_cast(float, u << 16);
}
static __device__ __forceinline__ float bfhi(unsigned int u) {
  return __builtin_bit_cast(float, u & 0xffff0000u);
}

// ---------------- in-degree histogram over dst ----------------------------
__global__ __launch_bounds__(256) void k_hist(const int* __restrict__ ei,
                                              int* __restrict__ cnt, int E) {
  int stride = gridDim.x * blockDim.x;
  for (int i = blockIdx.x * blockDim.x + threadIdx.x; i < E; i += stride)
    atomicAdd(&cnt[ei[E + i]], 1);
}

// ---------------- exclusive scan of cnt -> row_ptr ------------------------
__global__ __launch_bounds__(256) void k_scan1(const int* __restrict__ cnt,
                                               int* __restrict__ row_tmp,
                                               int* __restrict__ bsum, int N) {
  __shared__ int sd[256];
  const int tid = threadIdx.x;
  const int i = blockIdx.x * 256 + tid;
  int v = (i < N) ? cnt[i] : 0;
  sd[tid] = v;
  __syncthreads();
#pragma unroll
  for (int off = 1; off < 256; off <<= 1) {
    int t = (tid >= off) ? sd[tid - off] : 0;
    __syncthreads();
    sd[tid] += t;
    __syncthreads();
  }
  if (i < N) row_tmp[i] = sd[tid] - v;  // exclusive
  if (tid == 255) bsum[blockIdx.x] = sd[255];
}

__global__ __launch_bounds__(1024) void k_scan2(int* __restrict__ bsum, int nb) {
  __shared__ int sd[1024];
  const int t = threadIdx.x;
  int v = (t < nb) ? bsum[t] : 0;
  sd[t] = v;
  __syncthreads();
#pragma unroll
  for (int off = 1; off < 1024; off <<= 1) {
    int x = (t >= off) ? sd[t - off] : 0;
    __syncthreads();
    sd[t] += x;
    __syncthreads();
  }
  if (t < nb) bsum[t] = sd[t] - v;  // exclusive
}

// row_ptr/cursor from scan; dis[i] = (cnt[i]+1)^-0.5 folded in
__global__ __launch_bounds__(256) void k_scan3(const int* __restrict__ row_tmp,
                                               const int* __restrict__ bsum,
                                               const int* __restrict__ cnt,
                                               float* __restrict__ dis,
                                               int* __restrict__ row_ptr,
                                               int* __restrict__ cursor, int N,
                                               int E) {
  const int i = blockIdx.x * 256 + threadIdx.x;
  if (i < N) {
    int rp = row_tmp[i] + bsum[i >> 8];
    row_ptr[i] = rp;
    cursor[i] = rp;
    dis[i] = 1.0f / sqrtf((float)cnt[i] + 1.0f);
  }
  if (i == 0) row_ptr[N] = E;
}

// ---------------- CSR fill: col[pos] = src, bucketed by dst ---------------
__global__ __launch_bounds__(256) void k_fill(const int* __restrict__ ei,
                                              int* __restrict__ cursor,
                                              int* __restrict__ col, int E) {
  int stride = gridDim.x * blockDim.x;
  for (int e = blockIdx.x * blockDim.x + threadIdx.x; e < E; e += stride) {
    int s = ei[e];
    int d = ei[E + e];
    int pos = atomicAdd(&cursor[d], 1);
    col[pos] = s;
  }
}

// ---------------- graph boundaries from sorted batch ----------------------
__global__ __launch_bounds__(256) void k_bnd(const int* __restrict__ batch,
                                             int* __restrict__ gstart, int N) {
  const int i = blockIdx.x * 256 + threadIdx.x;
  if (i >= N) return;
  int b = batch[i];
  if (i == 0) {
    for (int g = 0; g <= b; ++g) gstart[g] = 0;
  } else {
    int p = batch[i - 1];
    for (int g = p + 1; g <= b; ++g) gstart[g] = i;
  }
  if (i == N - 1) {
    for (int g = b + 1; g <= 8; ++g) gstart[g] = N;
  }
}

// ---------------- pack W (KxM fp32) into B-fragment layout ----------------
__global__ __launch_bounds__(256) void k_pack(const float* __restrict__ W,
                                              unsigned short* __restrict__ Wp,
                                              int K, int M) {
  int t = blockIdx.x * 256 + threadIdx.x;
  int KT = K >> 5;
  int total = (M >> 4) * KT * 64;
  if (t >= total) return;
  int lane = t & 63;
  int tile = t >> 6;
  int kt = tile % KT;
  int ct = tile / KT;
  int c = ct * 16 + (lane & 15);
  int k0 = kt * 32 + (lane >> 4) * 8;
  unsigned short v[8];
#pragma unroll
  for (int j = 0; j < 8; ++j) v[j] = f2bf(W[(size_t)(k0 + j) * M + c]);
  ushort4* dst = (ushort4*)&Wp[(size_t)t * 8];
  dst[0] = make_ushort4(v[0], v[1], v[2], v[3]);
  dst[1] = make_ushort4(v[4], v[5], v[6], v[7]);
}

// ------- CSR agg, M=64: two half-waves handle alternating edges -----------
// P[d] = (EPI? relu(.+b):.) of Hin[d]*dis_d^2 + sum Hin[s]*dis_s*dis_d
template <bool EPI>
__global__ __launch_bounds__(256) void k_agg64(const int* __restrict__ row_ptr,
                                               const int* __restrict__ col,
                                               const float* __restrict__ dis,
                                               const unsigned short* __restrict__ Hin,
                                               const float* __restrict__ bias,
                                               unsigned short* __restrict__ Pout,
                                               int N) {
  const int lane = threadIdx.x & 63;
  const int sub = lane >> 5;
  const int cl = lane & 31;
  int d = blockIdx.x * 4 + (threadIdx.x >> 6);
  if (d >= N) return;
  const int cb = cl * 2;
  const float disd = dis[d];

  float a0 = 0.f, a1 = 0.f;
  if (sub == 0) {  // self-loop on half 0 only
    ushort2 u = *(const ushort2*)&Hin[(size_t)d * 64 + cb];
    float sc = disd * disd;
    a0 = bf2f(u.x) * sc;
    a1 = bf2f(u.y) * sc;
  }

  const int beg = row_ptr[d];
  const int end = row_ptr[d + 1];
  int j = beg + sub;
  for (; j + 2 < end; j += 4) {  // 2 edges per half in flight
    int s0 = col[j];
    int s1 = col[j + 2];
    float w0 = dis[s0] * disd;
    float w1 = dis[s1] * disd;
    ushort2 u0 = *(const ushort2*)&Hin[(size_t)s0 * 64 + cb];
    ushort2 u1 = *(const ushort2*)&Hin[(size_t)s1 * 64 + cb];
    a0 = fmaf(bf2f(u0.x), w0, a0);
    a1 = fmaf(bf2f(u0.y), w0, a1);
    a0 = fmaf(bf2f(u1.x), w1, a0);
    a1 = fmaf(bf2f(u1.y), w1, a1);
  }
  if (j < end) {
    int s0 = col[j];
    float w0 = dis[s0] * disd;
    ushort2 u0 = *(const ushort2*)&Hin[(size_t)s0 * 64 + cb];
    a0 = fmaf(bf2f(u0.x), w0, a0);
    a1 = fmaf(bf2f(u0.y), w0, a1);
  }

  a0 += __shfl_xor(a0, 32, 64);
  a1 += __shfl_xor(a1, 32, 64);
  if (sub == 0) {
    if (EPI) {
      a0 = fmaxf(a0 + bias[cb], 0.f);
      a1 = fmaxf(a1 + bias[cb + 1], 0.f);
    }
    *(ushort2*)&Pout[(size_t)d * 64 + cb] = make_ushort2(f2bf(a0), f2bf(a1));
  }
}

// ------- CSR agg, M=128/256: full wave per edge, unroll 4 -----------------
template <int M>
__global__ __launch_bounds__(256) void k_aggN(const int* __restrict__ row_ptr,
                                              const int* __restrict__ col,
                                              const float* __restrict__ dis,
                                              const unsigned short* __restrict__ Hin,
                                              unsigned short* __restrict__ Pout,
                                              int N) {
  constexpr int VEC = M / 64;
  const int lane = threadIdx.x & 63;
  int d = blockIdx.x * 4 + (threadIdx.x >> 6);
  if (d >= N) return;
  const int cb = lane * VEC;
  const float disd = dis[d];

  float acc[VEC];
  {
    const float sc = disd * disd;
    const unsigned short* hp = &Hin[(size_t)d * M + cb];
    if (VEC == 4) {
      ushort4 u = *(const ushort4*)hp;
      acc[0] = bf2f(u.x) * sc; acc[1] = bf2f(u.y) * sc;
      acc[2] = bf2f(u.z) * sc; acc[3] = bf2f(u.w) * sc;
    } else {
      ushort2 u = *(const ushort2*)hp;
      acc[0] = bf2f(u.x) * sc; acc[1] = bf2f(u.y) * sc;
    }
  }

  const int beg = row_ptr[d];
  const int end = row_ptr[d + 1];
  int j = beg;
  for (; j + 3 < end; j += 4) {
    int s[4];
    float w[4];
#pragma unroll
    for (int q = 0; q < 4; ++q) s[q] = col[j + q];
#pragma unroll
    for (int q = 0; q < 4; ++q) w[q] = dis[s[q]] * disd;
    if (VEC == 4) {
      ushort4 u[4];
#pragma unroll
      for (int q = 0; q < 4; ++q) u[q] = *(const ushort4*)&Hin[(size_t)s[q] * M + cb];
#pragma unroll
      for (int q = 0; q < 4; ++q) {
        acc[0] = fmaf(bf2f(u[q].x), w[q], acc[0]);
        acc[1] = fmaf(bf2f(u[q].y), w[q], acc[1]);
        acc[2] = fmaf(bf2f(u[q].z), w[q], acc[2]);
        acc[3] = fmaf(bf2f(u[q].w), w[q], acc[3]);
      }
    } else {
      ushort2 u[4];
#pragma unroll
      for (int q = 0; q < 4; ++q) u[q] = *(const ushort2*)&Hin[(size_t)s[q] * M + cb];
#pragma unroll
      for (int q = 0; q < 4; ++q) {
        acc[0] = fmaf(bf2f(u[q].x), w[q], acc[0]);
        acc[1] = fmaf(bf2f(u[q].y), w[q], acc[1]);
      }
    }
  }
  for (; j < end; ++j) {
    int s = col[j];
    float w = dis[s] * disd;
    const unsigned short* hp = &Hin[(size_t)s * M + cb];
    if (VEC == 4) {
      ushort4 u = *(const ushort4*)hp;
      acc[0] = fmaf(bf2f(u.x), w, acc[0]);
      acc[1] = fmaf(bf2f(u.y), w, acc[1]);
      acc[2] = fmaf(bf2f(u.z), w, acc[2]);
      acc[3] = fmaf(bf2f(u.w), w, acc[3]);
    } else {
      ushort2 u = *(const ushort2*)hp;
      acc[0] = fmaf(bf2f(u.x), w, acc[0]);
      acc[1] = fmaf(bf2f(u.y), w, acc[1]);
    }
  }

  unsigned short* pp = &Pout[(size_t)d * M + cb];
  if (VEC == 4)
    *(ushort4*)pp = make_ushort4(f2bf(acc[0]), f2bf(acc[1]), f2bf(acc[2]), f2bf(acc[3]));
  else
    *(ushort2*)pp = make_ushort2(f2bf(acc[0]), f2bf(acc[1]));
}

// ---------------- MFMA GEMM: Hout = [relu](A @ W [+ b]), bf16 out ---------
// A frag: lane holds A[row0+(lane&15)][kt*32+(lane>>4)*8 + 0..7]
// D frag: row=(lane>>4)*4+reg, col=lane&15
template <int K, int M, bool F32IN, bool BIAS>
__global__ __launch_bounds__(256) void k_mm(const void* __restrict__ Ap,
                                            const unsigned short* __restrict__ Wp,
                                            const float* __restrict__ bias,
                                            unsigned short* __restrict__ Hout,
                                            int N) {
  constexpr int KT = K / 32, CT = M / 16;
  const int lane = threadIdx.x & 63;
  const int wid = threadIdx.x >> 6;
  int row0 = (blockIdx.x * 4 + wid) * 16;
  row0 = __builtin_amdgcn_readfirstlane(row0);
  if (row0 >= N) return;
  const int r = lane & 15;
  const int kh = lane >> 4;

  int arow = row0 + r;
  if (arow >= N) arow = N - 1;

  f32x4 acc[CT];
#pragma unroll
  for (int ct = 0; ct < CT; ++ct) acc[ct] = (f32x4){0.f, 0.f, 0.f, 0.f};

#pragma unroll
  for (int kt = 0; kt < KT; ++kt) {
    short8v a;
    if (F32IN) {
      const float* Af = (const float*)Ap;
      const float* p = &Af[(size_t)arow * K + kt * 32 + kh * 8];
      float4 f0 = *(const float4*)p;
      float4 f1 = *(const float4*)(p + 4);
      a[0] = (short)f2bf(f0.x); a[1] = (short)f2bf(f0.y);
      a[2] = (short)f2bf(f0.z); a[3] = (short)f2bf(f0.w);
      a[4] = (short)f2bf(f1.x); a[5] = (short)f2bf(f1.y);
      a[6] = (short)f2bf(f1.z); a[7] = (short)f2bf(f1.w);
    } else {
      const unsigned short* Ab = (const unsigned short*)Ap;
      a = *(const short8v*)&Ab[(size_t)arow * K + kt * 32 + kh * 8];
    }
#pragma unroll
    for (int ct = 0; ct < CT; ++ct) {
      short8v b = *(const short8v*)&Wp[(size_t)((ct * KT + kt) * 64 + lane) * 8];
      acc[ct] = __builtin_amdgcn_mfma_f32_16x16x32_bf16(a, b, acc[ct], 0, 0, 0);
    }
  }

  const int orow0 = row0 + kh * 4;
#pragma unroll
  for (int ct = 0; ct < CT; ++ct) {
    const int c = ct * 16 + r;
    const float bv = BIAS ? bias[c] : 0.f;
#pragma unroll
    for (int reg = 0; reg < 4; ++reg) {
      int row = orow0 + reg;
      if (row < N) {
        float v = acc[ct][reg] + bv;
        if (BIAS) v = fmaxf(v, 0.f);
        Hout[(size_t)row * M + c] = f2bf(v);
      }
    }
  }
}

// ---------------- pooling: per-graph segmented sum over sorted rows -------
// grid (PB, 8); 256 thr = 32 col-lanes x 8 row-streams; 16B loads.
__global__ __launch_bounds__(256) void k_pool2(const unsigned short* __restrict__ H4,
                                               const int* __restrict__ gstart,
                                               float* __restrict__ pooled) {
  __shared__ float sd[8][256];
  const int g = blockIdx.y;
  const int s = gstart[g], e = gstart[g + 1];
  if (s >= e) return;  // uniform per block
  const int PB = gridDim.x;
  const int chunk = (e - s + PB - 1) / PB;
  const int r0 = s + blockIdx.x * chunk;
  const int r1 = min(e, r0 + chunk);

  const int t = threadIdx.x;
  const int rs = t >> 5;
  const int cl = t & 31;
  const int cb = cl * 8;

  float a[8];
#pragma unroll
  for (int k = 0; k < 8; ++k) a[k] = 0.f;

  for (int r = r0 + rs; r < r1; r += 8) {
    uint4 u = *(const uint4*)&H4[(size_t)r * 256 + cb];
    a[0] += bflo(u.x); a[1] += bfhi(u.x);
    a[2] += bflo(u.y); a[3] += bfhi(u.y);
    a[4] += bflo(u.z); a[5] += bfhi(u.z);
    a[6] += bflo(u.w); a[7] += bfhi(u.w);
  }
#pragma unroll
  for (int k = 0; k < 8; ++k) sd[rs][cb + k] = a[k];
  __syncthreads();
  float v = 0.f;
#pragma unroll
  for (int q = 0; q < 8; ++q) v += sd[q][t];
  atomicAdd(&pooled[g * 256 + t], v);
}

// ---------------- final FC: out[g] = pooled[g]/cnt . Wfc + bfc ------------
__global__ __launch_bounds__(256) void k_final(const float* __restrict__ pooled,
                                               const int* __restrict__ gstart,
                                               const float* __restrict__ Wfc,
                                               const float* __restrict__ bfc,
                                               float* __restrict__ out) {
  __shared__ float red[4];
  const int t = threadIdx.x;
  for (int g = 0; g < 8; ++g) {
    float cg = (float)(gstart[g + 1] - gstart[g]);
    float v = pooled[g * 256 + t] / cg * Wfc[t];
#pragma unroll
    for (int off = 32; off > 0; off >>= 1) v += __shfl_down(v, off, 64);
    if ((t & 63) == 0) red[t >> 6] = v;
    __syncthreads();
    if (t == 0) out[g] = red[0] + red[1] + red[2] + red[3] + bfc[0];
    __syncthreads();
  }
}

extern "C" void kernel_launch(void* const* d_in, const int* in_sizes, int n_in,
                              void* d_out, int out_size, void* d_ws,
                              size_t ws_size, hipStream_t stream) {
  const float* x = (const float*)d_in[0];
  const int* ei = (const int*)d_in[1];
  const int* batch = (const int*)d_in[2];
  const float* W1 = (const float*)d_in[3];
  const float* b1 = (const float*)d_in[4];
  const float* W2 = (const float*)d_in[5];
  const float* b2 = (const float*)d_in[6];
  const float* W3 = (const float*)d_in[7];
  const float* b3 = (const float*)d_in[8];
  const float* Wfc = (const float*)d_in[9];
  const float* bfc = (const float*)d_in[10];
  float* out = (float*)d_out;

  const int N = in_sizes[0] / 128;
  const int E = in_sizes[1] / 2;
  const int nb = (N + 255) / 256;

  // -------- workspace layout (4-byte units), ~134 MB total --------
  float* ws = (float*)d_ws;
  size_t o = 0;
  float* dis = ws + o;            o += (size_t)N;
  int* cnt = (int*)(ws + o);      o += (size_t)N;
  int* row_tmp = (int*)(ws + o);  o += (size_t)N;
  int* bsum = (int*)(ws + o);     o += 1024;
  int* row_ptr = (int*)(ws + o);  o += (size_t)N + 1;
  int* cursor = (int*)(ws + o);   o += (size_t)N;
  int* col = (int*)(ws + o);      o += (size_t)E;
  float* pooled = ws + o;         o += 2048;
  int* gstart = (int*)(ws + o);   o += 16;
  unsigned short* Wp1 = (unsigned short*)(ws + o); o += 4096;   // 128x64 bf16
  unsigned short* Wp2 = (unsigned short*)(ws + o); o += 4096;   // 64x128
  unsigned short* Wp3 = (unsigned short*)(ws + o); o += 16384;  // 128x256
  o = (o + 63) & ~(size_t)63;
  unsigned short* bufA = (unsigned short*)(ws + o); o += (size_t)N * 32;  // t1 / P2 (64ch)
  unsigned short* bufB = (unsigned short*)(ws + o); o += (size_t)N * 32;  // h2 (64ch)
  unsigned short* bufC = (unsigned short*)(ws + o); o += (size_t)N * 64;  // h3 (128ch)
  unsigned short* bufD = (unsigned short*)(ws + o); o += (size_t)N * 64;  // P3 (128ch)
  unsigned short* bufE = (unsigned short*)(ws + o); o += (size_t)N * 128; // h4 (256ch)

  hipMemsetAsync(cnt, 0, (size_t)N * sizeof(int), stream);
  hipMemsetAsync(pooled, 0, 2048 * sizeof(float), stream);

  k_hist<<<2048, 256, 0, stream>>>(ei, cnt, E);
  k_scan1<<<nb, 256, 0, stream>>>(cnt, row_tmp, bsum, N);
  k_scan2<<<1, 1024, 0, stream>>>(bsum, nb);
  k_scan3<<<nb, 256, 0, stream>>>(row_tmp, bsum, cnt, dis, row_ptr, cursor, N, E);
  k_fill<<<2048, 256, 0, stream>>>(ei, cursor, col, E);
  k_bnd<<<nb, 256, 0, stream>>>(batch, gstart, N);

  k_pack<<<(128 * 64 / 8 + 255) / 256, 256, 0, stream>>>(W1, Wp1, 128, 64);
  k_pack<<<(64 * 128 / 8 + 255) / 256, 256, 0, stream>>>(W2, Wp2, 64, 128);
  k_pack<<<(128 * 256 / 8 + 255) / 256, 256, 0, stream>>>(W3, Wp3, 128, 256);

  const int ablocks = (N + 3) / 4;
  const int mblocks = (N + 63) / 64;
  // L1: t1 = x @ W1 (fp32 in, raw out); h2 = relu(agg(t1) + b1)
  k_mm<128, 64, true, false><<<mblocks, 256, 0, stream>>>(x, Wp1, nullptr, bufA, N);
  k_agg64<true><<<ablocks, 256, 0, stream>>>(row_ptr, col, dis, bufA, b1, bufB, N);
  // L2: P2 = agg(h2); h3 = relu(P2 @ W2 + b2)
  k_agg64<false><<<ablocks, 256, 0, stream>>>(row_ptr, col, dis, bufB, nullptr, bufA, N);
  k_mm<64, 128, false, true><<<mblocks, 256, 0, stream>>>(bufA, Wp2, b2, bufC, N);
  // L3: P3 = agg(h3); h4 = relu(P3 @ W3 + b3)
  k_aggN<128><<<ablocks, 256, 0, stream>>>(row_ptr, col, dis, bufC, bufD, N);
  k_mm<128, 256, false, true><<<mblocks, 256, 0, stream>>>(bufD, Wp3, b3, bufE, N);

  k_pool2<<<dim3(128, 8), 256, 0, stream>>>(bufE, gstart, pooled);
  k_final<<<1, 256, 0, stream>>>(pooled, gstart, Wfc, bfc, out);
}

// Round 6
// 420.628 us; speedup vs baseline: 9.5108x; 1.0874x over previous
//
#include <hip/hip_runtime.h>
#include <hip/hip_bf16.h>

typedef __attribute__((ext_vector_type(8))) short short8v;   // 8 bf16 (4 VGPR)
typedef __attribute__((ext_vector_type(4))) float f32x4;

static __device__ __forceinline__ unsigned short f2bf(float f) {
  __hip_bfloat16 b = __float2bfloat16(f);  // round-to-nearest-even
  return *reinterpret_cast<unsigned short*>(&b);
}
static __device__ __forceinline__ float bf2f(unsigned short u) {
  unsigned int x = ((unsigned int)u) << 16;
  return __builtin_bit_cast(float, x);
}
static __device__ __forceinline__ float bflo(unsigned int u) {
  return __builtin_bit_cast(float, u << 16);
}
static __device__ __forceinline__ float bfhi(unsigned int u) {
  return __builtin_bit_cast(float, u & 0xffff0000u);
}

// ---------------- in-degree histogram over dst ----------------------------
__global__ __launch_bounds__(256) void k_hist(const int* __restrict__ ei,
                                              int* __restrict__ cnt, int E) {
  int stride = gridDim.x * blockDim.x;
  for (int i = blockIdx.x * blockDim.x + threadIdx.x; i < E; i += stride)
    atomicAdd(&cnt[ei[E + i]], 1);
}

// ---------------- exclusive scan of cnt -> row_ptr ------------------------
__global__ __launch_bounds__(256) void k_scan1(const int* __restrict__ cnt,
                                               int* __restrict__ row_tmp,
                                               int* __restrict__ bsum, int N) {
  __shared__ int sd[256];
  const int tid = threadIdx.x;
  const int i = blockIdx.x * 256 + tid;
  int v = (i < N) ? cnt[i] : 0;
  sd[tid] = v;
  __syncthreads();
#pragma unroll
  for (int off = 1; off < 256; off <<= 1) {
    int t = (tid >= off) ? sd[tid - off] : 0;
    __syncthreads();
    sd[tid] += t;
    __syncthreads();
  }
  if (i < N) row_tmp[i] = sd[tid] - v;  // exclusive
  if (tid == 255) bsum[blockIdx.x] = sd[255];
}

__global__ __launch_bounds__(1024) void k_scan2(int* __restrict__ bsum, int nb) {
  __shared__ int sd[1024];
  const int t = threadIdx.x;
  int v = (t < nb) ? bsum[t] : 0;
  sd[t] = v;
  __syncthreads();
#pragma unroll
  for (int off = 1; off < 1024; off <<= 1) {
    int x = (t >= off) ? sd[t - off] : 0;
    __syncthreads();
    sd[t] += x;
    __syncthreads();
  }
  if (t < nb) bsum[t] = sd[t] - v;  // exclusive
}

// row_ptr/cursor + dis + graph boundaries, one pass over N
__global__ __launch_bounds__(256) void k_scan3(const int* __restrict__ row_tmp,
                                               const int* __restrict__ bsum,
                                               const int* __restrict__ cnt,
                                               const int* __restrict__ batch,
                                               float* __restrict__ dis,
                                               int* __restrict__ row_ptr,
                                               int* __restrict__ cursor,
                                               int* __restrict__ gstart, int N,
                                               int E) {
  const int i = blockIdx.x * 256 + threadIdx.x;
  if (i < N) {
    int rp = row_tmp[i] + bsum[i >> 8];
    row_ptr[i] = rp;
    cursor[i] = rp;
    dis[i] = 1.0f / sqrtf((float)cnt[i] + 1.0f);
    int b = batch[i];
    if (i == 0) {
      for (int g = 0; g <= b; ++g) gstart[g] = 0;
    } else {
      int p = batch[i - 1];
      for (int g = p + 1; g <= b; ++g) gstart[g] = i;
    }
    if (i == N - 1)
      for (int g = b + 1; g <= 8; ++g) gstart[g] = N;
  }
  if (i == 0) row_ptr[N] = E;
}

// ---------------- CSR fill: col[pos] = src, bucketed by dst ---------------
__global__ __launch_bounds__(256) void k_fill(const int* __restrict__ ei,
                                              int* __restrict__ cursor,
                                              int* __restrict__ col, int E) {
  int stride = gridDim.x * blockDim.x;
  for (int e = blockIdx.x * blockDim.x + threadIdx.x; e < E; e += stride) {
    int s = ei[e];
    int d = ei[E + e];
    int pos = atomicAdd(&cursor[d], 1);
    col[pos] = s;
  }
}

// ---------------- pack W (KxM fp32) into B-fragment layout ----------------
static __device__ __forceinline__ void pack_one(const float* __restrict__ W,
                                                unsigned short* __restrict__ Wp,
                                                int K, int M, int t) {
  int KT = K >> 5;
  int lane = t & 63;
  int tile = t >> 6;
  int kt = tile % KT;
  int ct = tile / KT;
  int c = ct * 16 + (lane & 15);
  int k0 = kt * 32 + (lane >> 4) * 8;
  unsigned short v[8];
#pragma unroll
  for (int j = 0; j < 8; ++j) v[j] = f2bf(W[(size_t)(k0 + j) * M + c]);
  ushort4* dst = (ushort4*)&Wp[(size_t)t * 8];
  dst[0] = make_ushort4(v[0], v[1], v[2], v[3]);
  dst[1] = make_ushort4(v[4], v[5], v[6], v[7]);
}

__global__ __launch_bounds__(256) void k_packall(
    const float* __restrict__ W1, const float* __restrict__ W2,
    const float* __restrict__ W3, unsigned short* __restrict__ Wp1,
    unsigned short* __restrict__ Wp2, unsigned short* __restrict__ Wp3) {
  int t = blockIdx.x * 256 + threadIdx.x;
  if (t < 1024)
    pack_one(W1, Wp1, 128, 64, t);          // 4*4*64 frags
  else if (t < 2048)
    pack_one(W2, Wp2, 64, 128, t - 1024);   // 8*2*64
  else if (t < 6144)
    pack_one(W3, Wp3, 128, 256, t - 2048);  // 16*4*64
}

// ------- CSR agg, M=64: wave/dst; 8 sub-waves x 8 lanes x 8ch (16B loads) -
// P[d] = (EPI? relu(.+b):.) of Hin[d]*dis_d^2 + sum Hin[s]*dis_s*dis_d
template <bool EPI>
__global__ __launch_bounds__(256) void k_agg64(const int* __restrict__ row_ptr,
                                               const int* __restrict__ col,
                                               const float* __restrict__ dis,
                                               const unsigned short* __restrict__ Hin,
                                               const float* __restrict__ bias,
                                               unsigned short* __restrict__ Pout,
                                               int N) {
  const int lane = threadIdx.x & 63;
  int d = blockIdx.x * 4 + (threadIdx.x >> 6);
  if (d >= N) return;
  const int q = lane >> 3;   // sub-wave 0..7, one edge each
  const int cl = lane & 7;   // 8 lanes x 8ch = 64 channels
  const int cb = cl * 8;
  const float disd = dis[d];
  const int beg = row_ptr[d];
  const int end = row_ptr[d + 1];
  const int deg = end - beg;
  const int nedge = min(deg, 64);

  // lane-parallel prefetch of all indices + norm weights for this row
  int s_l = d;
  float w_l = 0.f;
  if (lane < nedge) {
    s_l = col[beg + lane];
    w_l = dis[s_l] * disd;
  }

  float acc[8];
#pragma unroll
  for (int k = 0; k < 8; ++k) acc[k] = 0.f;
  if (q == 0) {  // self-loop on sub-wave 0
    uint4 u = *(const uint4*)&Hin[(size_t)d * 64 + cb];
    const float sc = disd * disd;
    acc[0] = bflo(u.x) * sc; acc[1] = bfhi(u.x) * sc;
    acc[2] = bflo(u.y) * sc; acc[3] = bfhi(u.y) * sc;
    acc[4] = bflo(u.z) * sc; acc[5] = bfhi(u.z) * sc;
    acc[6] = bflo(u.w) * sc; acc[7] = bfhi(u.w) * sc;
  }

  const int padded = (nedge + 15) & ~15;  // 16 edges per iter (8 subwaves x2)
  for (int base = 0; base < padded; base += 16) {
    int e0 = base + q, e1 = base + 8 + q;
    int s0 = __shfl(s_l, e0, 64);
    float w0 = __shfl(w_l, e0, 64);
    int s1 = __shfl(s_l, e1, 64);
    float w1 = __shfl(w_l, e1, 64);
    if (e0 >= nedge) { s0 = d; w0 = 0.f; }
    if (e1 >= nedge) { s1 = d; w1 = 0.f; }
    uint4 u0 = *(const uint4*)&Hin[(size_t)s0 * 64 + cb];
    uint4 u1 = *(const uint4*)&Hin[(size_t)s1 * 64 + cb];
    acc[0] = fmaf(bflo(u0.x), w0, acc[0]); acc[1] = fmaf(bfhi(u0.x), w0, acc[1]);
    acc[2] = fmaf(bflo(u0.y), w0, acc[2]); acc[3] = fmaf(bfhi(u0.y), w0, acc[3]);
    acc[4] = fmaf(bflo(u0.z), w0, acc[4]); acc[5] = fmaf(bfhi(u0.z), w0, acc[5]);
    acc[6] = fmaf(bflo(u0.w), w0, acc[6]); acc[7] = fmaf(bfhi(u0.w), w0, acc[7]);
    acc[0] = fmaf(bflo(u1.x), w1, acc[0]); acc[1] = fmaf(bfhi(u1.x), w1, acc[1]);
    acc[2] = fmaf(bflo(u1.y), w1, acc[2]); acc[3] = fmaf(bfhi(u1.y), w1, acc[3]);
    acc[4] = fmaf(bflo(u1.z), w1, acc[4]); acc[5] = fmaf(bfhi(u1.z), w1, acc[5]);
    acc[6] = fmaf(bflo(u1.w), w1, acc[6]); acc[7] = fmaf(bfhi(u1.w), w1, acc[7]);
  }
  if (deg > 64) {  // essentially never (Poisson deg~8); correctness tail
    for (int j = beg + 64 + q; j < end; j += 8) {
      int s = col[j];
      float w = dis[s] * disd;
      uint4 u = *(const uint4*)&Hin[(size_t)s * 64 + cb];
      acc[0] = fmaf(bflo(u.x), w, acc[0]); acc[1] = fmaf(bfhi(u.x), w, acc[1]);
      acc[2] = fmaf(bflo(u.y), w, acc[2]); acc[3] = fmaf(bfhi(u.y), w, acc[3]);
      acc[4] = fmaf(bflo(u.z), w, acc[4]); acc[5] = fmaf(bfhi(u.z), w, acc[5]);
      acc[6] = fmaf(bflo(u.w), w, acc[6]); acc[7] = fmaf(bfhi(u.w), w, acc[7]);
    }
  }

#pragma unroll
  for (int k = 0; k < 8; ++k) {
    acc[k] += __shfl_xor(acc[k], 8, 64);
    acc[k] += __shfl_xor(acc[k], 16, 64);
    acc[k] += __shfl_xor(acc[k], 32, 64);
  }
  if (q == 0) {
    if (EPI) {
#pragma unroll
      for (int k = 0; k < 8; ++k) acc[k] = fmaxf(acc[k] + bias[cb + k], 0.f);
    }
    uint4 o;
    o.x = (unsigned)f2bf(acc[0]) | ((unsigned)f2bf(acc[1]) << 16);
    o.y = (unsigned)f2bf(acc[2]) | ((unsigned)f2bf(acc[3]) << 16);
    o.z = (unsigned)f2bf(acc[4]) | ((unsigned)f2bf(acc[5]) << 16);
    o.w = (unsigned)f2bf(acc[6]) | ((unsigned)f2bf(acc[7]) << 16);
    *(uint4*)&Pout[(size_t)d * 64 + cb] = o;
  }
}

// ------- CSR agg, M=128: wave/dst; 4 sub-waves x 16 lanes x 8ch -----------
__global__ __launch_bounds__(256) void k_agg128(const int* __restrict__ row_ptr,
                                                const int* __restrict__ col,
                                                const float* __restrict__ dis,
                                                const unsigned short* __restrict__ Hin,
                                                unsigned short* __restrict__ Pout,
                                                int N) {
  const int lane = threadIdx.x & 63;
  int d = blockIdx.x * 4 + (threadIdx.x >> 6);
  if (d >= N) return;
  const int q = lane >> 4;    // sub-wave 0..3
  const int cl = lane & 15;   // 16 lanes x 8ch = 128 channels
  const int cb = cl * 8;
  const float disd = dis[d];
  const int beg = row_ptr[d];
  const int end = row_ptr[d + 1];
  const int deg = end - beg;
  const int nedge = min(deg, 64);

  int s_l = d;
  float w_l = 0.f;
  if (lane < nedge) {
    s_l = col[beg + lane];
    w_l = dis[s_l] * disd;
  }

  float acc[8];
#pragma unroll
  for (int k = 0; k < 8; ++k) acc[k] = 0.f;
  if (q == 0) {  // self-loop
    uint4 u = *(const uint4*)&Hin[(size_t)d * 128 + cb];
    const float sc = disd * disd;
    acc[0] = bflo(u.x) * sc; acc[1] = bfhi(u.x) * sc;
    acc[2] = bflo(u.y) * sc; acc[3] = bfhi(u.y) * sc;
    acc[4] = bflo(u.z) * sc; acc[5] = bfhi(u.z) * sc;
    acc[6] = bflo(u.w) * sc; acc[7] = bfhi(u.w) * sc;
  }

  const int padded = (nedge + 7) & ~7;  // 8 edges per iter (4 subwaves x2)
  for (int base = 0; base < padded; base += 8) {
    int e0 = base + q, e1 = base + 4 + q;
    int s0 = __shfl(s_l, e0, 64);
    float w0 = __shfl(w_l, e0, 64);
    int s1 = __shfl(s_l, e1, 64);
    float w1 = __shfl(w_l, e1, 64);
    if (e0 >= nedge) { s0 = d; w0 = 0.f; }
    if (e1 >= nedge) { s1 = d; w1 = 0.f; }
    uint4 u0 = *(const uint4*)&Hin[(size_t)s0 * 128 + cb];
    uint4 u1 = *(const uint4*)&Hin[(size_t)s1 * 128 + cb];
    acc[0] = fmaf(bflo(u0.x), w0, acc[0]); acc[1] = fmaf(bfhi(u0.x), w0, acc[1]);
    acc[2] = fmaf(bflo(u0.y), w0, acc[2]); acc[3] = fmaf(bfhi(u0.y), w0, acc[3]);
    acc[4] = fmaf(bflo(u0.z), w0, acc[4]); acc[5] = fmaf(bfhi(u0.z), w0, acc[5]);
    acc[6] = fmaf(bflo(u0.w), w0, acc[6]); acc[7] = fmaf(bfhi(u0.w), w0, acc[7]);
    acc[0] = fmaf(bflo(u1.x), w1, acc[0]); acc[1] = fmaf(bfhi(u1.x), w1, acc[1]);
    acc[2] = fmaf(bflo(u1.y), w1, acc[2]); acc[3] = fmaf(bfhi(u1.y), w1, acc[3]);
    acc[4] = fmaf(bflo(u1.z), w1, acc[4]); acc[5] = fmaf(bfhi(u1.z), w1, acc[5]);
    acc[6] = fmaf(bflo(u1.w), w1, acc[6]); acc[7] = fmaf(bfhi(u1.w), w1, acc[7]);
  }
  if (deg > 64) {
    for (int j = beg + 64 + q; j < end; j += 4) {
      int s = col[j];
      float w = dis[s] * disd;
      uint4 u = *(const uint4*)&Hin[(size_t)s * 128 + cb];
      acc[0] = fmaf(bflo(u.x), w, acc[0]); acc[1] = fmaf(bfhi(u.x), w, acc[1]);
      acc[2] = fmaf(bflo(u.y), w, acc[2]); acc[3] = fmaf(bfhi(u.y), w, acc[3]);
      acc[4] = fmaf(bflo(u.z), w, acc[4]); acc[5] = fmaf(bfhi(u.z), w, acc[5]);
      acc[6] = fmaf(bflo(u.w), w, acc[6]); acc[7] = fmaf(bfhi(u.w), w, acc[7]);
    }
  }

#pragma unroll
  for (int k = 0; k < 8; ++k) {
    acc[k] += __shfl_xor(acc[k], 16, 64);
    acc[k] += __shfl_xor(acc[k], 32, 64);
  }
  if (q == 0) {
    uint4 o;
    o.x = (unsigned)f2bf(acc[0]) | ((unsigned)f2bf(acc[1]) << 16);
    o.y = (unsigned)f2bf(acc[2]) | ((unsigned)f2bf(acc[3]) << 16);
    o.z = (unsigned)f2bf(acc[4]) | ((unsigned)f2bf(acc[5]) << 16);
    o.w = (unsigned)f2bf(acc[6]) | ((unsigned)f2bf(acc[7]) << 16);
    *(uint4*)&Pout[(size_t)d * 128 + cb] = o;
  }
}

// ---------------- MFMA GEMM: Hout = [relu](A @ W [+ b]), bf16 out ---------
// A frag: lane holds A[row0+(lane&15)][kt*32+(lane>>4)*8 + 0..7]
// D frag: row=(lane>>4)*4+reg, col=lane&15
template <int K, int M, bool F32IN, bool BIAS>
__global__ __launch_bounds__(256) void k_mm(const void* __restrict__ Ap,
                                            const unsigned short* __restrict__ Wp,
                                            const float* __restrict__ bias,
                                            unsigned short* __restrict__ Hout,
                                            int N) {
  constexpr int KT = K / 32, CT = M / 16;
  const int lane = threadIdx.x & 63;
  const int wid = threadIdx.x >> 6;
  int row0 = (blockIdx.x * 4 + wid) * 16;
  row0 = __builtin_amdgcn_readfirstlane(row0);
  if (row0 >= N) return;
  const int r = lane & 15;
  const int kh = lane >> 4;

  int arow = row0 + r;
  if (arow >= N) arow = N - 1;

  f32x4 acc[CT];
#pragma unroll
  for (int ct = 0; ct < CT; ++ct) acc[ct] = (f32x4){0.f, 0.f, 0.f, 0.f};

#pragma unroll
  for (int kt = 0; kt < KT; ++kt) {
    short8v a;
    if (F32IN) {
      const float* Af = (const float*)Ap;
      const float* p = &Af[(size_t)arow * K + kt * 32 + kh * 8];
      float4 f0 = *(const float4*)p;
      float4 f1 = *(const float4*)(p + 4);
      a[0] = (short)f2bf(f0.x); a[1] = (short)f2bf(f0.y);
      a[2] = (short)f2bf(f0.z); a[3] = (short)f2bf(f0.w);
      a[4] = (short)f2bf(f1.x); a[5] = (short)f2bf(f1.y);
      a[6] = (short)f2bf(f1.z); a[7] = (short)f2bf(f1.w);
    } else {
      const unsigned short* Ab = (const unsigned short*)Ap;
      a = *(const short8v*)&Ab[(size_t)arow * K + kt * 32 + kh * 8];
    }
#pragma unroll
    for (int ct = 0; ct < CT; ++ct) {
      short8v b = *(const short8v*)&Wp[(size_t)((ct * KT + kt) * 64 + lane) * 8];
      acc[ct] = __builtin_amdgcn_mfma_f32_16x16x32_bf16(a, b, acc[ct], 0, 0, 0);
    }
  }

  const int orow0 = row0 + kh * 4;
#pragma unroll
  for (int ct = 0; ct < CT; ++ct) {
    const int c = ct * 16 + r;
    const float bv = BIAS ? bias[c] : 0.f;
#pragma unroll
    for (int reg = 0; reg < 4; ++reg) {
      int row = orow0 + reg;
      if (row < N) {
        float v = acc[ct][reg] + bv;
        if (BIAS) v = fmaxf(v, 0.f);
        Hout[(size_t)row * M + c] = f2bf(v);
      }
    }
  }
}

// ---------------- pooling: per-graph segmented sum over sorted rows -------
__global__ __launch_bounds__(256) void k_pool2(const unsigned short* __restrict__ H4,
                                               const int* __restrict__ gstart,
                                               float* __restrict__ pooled) {
  __shared__ float sd[8][256];
  const int g = blockIdx.y;
  const int s = gstart[g], e = gstart[g + 1];
  if (s >= e) return;  // uniform per block
  const int PB = gridDim.x;
  const int chunk = (e - s + PB - 1) / PB;
  const int r0 = s + blockIdx.x * chunk;
  const int r1 = min(e, r0 + chunk);

  const int t = threadIdx.x;
  const int rs = t >> 5;
  const int cl = t & 31;
  const int cb = cl * 8;

  float a[8];
#pragma unroll
  for (int k = 0; k < 8; ++k) a[k] = 0.f;

  for (int r = r0 + rs; r < r1; r += 8) {
    uint4 u = *(const uint4*)&H4[(size_t)r * 256 + cb];
    a[0] += bflo(u.x); a[1] += bfhi(u.x);
    a[2] += bflo(u.y); a[3] += bfhi(u.y);
    a[4] += bflo(u.z); a[5] += bfhi(u.z);
    a[6] += bflo(u.w); a[7] += bfhi(u.w);
  }
#pragma unroll
  for (int k = 0; k < 8; ++k) sd[rs][cb + k] = a[k];
  __syncthreads();
  float v = 0.f;
#pragma unroll
  for (int q = 0; q < 8; ++q) v += sd[q][t];
  atomicAdd(&pooled[g * 256 + t], v);
}

// ---------------- final FC: out[g] = pooled[g]/cnt . Wfc + bfc ------------
__global__ __launch_bounds__(256) void k_final(const float* __restrict__ pooled,
                                               const int* __restrict__ gstart,
                                               const float* __restrict__ Wfc,
                                               const float* __restrict__ bfc,
                                               float* __restrict__ out) {
  __shared__ float red[4];
  const int t = threadIdx.x;
  for (int g = 0; g < 8; ++g) {
    float cg = (float)(gstart[g + 1] - gstart[g]);
    float v = pooled[g * 256 + t] / cg * Wfc[t];
#pragma unroll
    for (int off = 32; off > 0; off >>= 1) v += __shfl_down(v, off, 64);
    if ((t & 63) == 0) red[t >> 6] = v;
    __syncthreads();
    if (t == 0) out[g] = red[0] + red[1] + red[2] + red[3] + bfc[0];
    __syncthreads();
  }
}

extern "C" void kernel_launch(void* const* d_in, const int* in_sizes, int n_in,
                              void* d_out, int out_size, void* d_ws,
                              size_t ws_size, hipStream_t stream) {
  const float* x = (const float*)d_in[0];
  const int* ei = (const int*)d_in[1];
  const int* batch = (const int*)d_in[2];
  const float* W1 = (const float*)d_in[3];
  const float* b1 = (const float*)d_in[4];
  const float* W2 = (const float*)d_in[5];
  const float* b2 = (const float*)d_in[6];
  const float* W3 = (const float*)d_in[7];
  const float* b3 = (const float*)d_in[8];
  const float* Wfc = (const float*)d_in[9];
  const float* bfc = (const float*)d_in[10];
  float* out = (float*)d_out;

  const int N = in_sizes[0] / 128;
  const int E = in_sizes[1] / 2;
  const int nb = (N + 255) / 256;

  // -------- workspace layout (4-byte units), ~134 MB total --------
  float* ws = (float*)d_ws;
  size_t o = 0;
  float* dis = ws + o;            o += (size_t)N;
  int* cnt = (int*)(ws + o);      o += (size_t)N;
  int* row_tmp = (int*)(ws + o);  o += (size_t)N;
  int* bsum = (int*)(ws + o);     o += 1024;
  int* row_ptr = (int*)(ws + o);  o += (size_t)N + 1;
  int* cursor = (int*)(ws + o);   o += (size_t)N;
  int* col = (int*)(ws + o);      o += (size_t)E;
  float* pooled = ws + o;         o += 2048;
  int* gstart = (int*)(ws + o);   o += 16;
  unsigned short* Wp1 = (unsigned short*)(ws + o); o += 4096;   // 128x64 bf16
  unsigned short* Wp2 = (unsigned short*)(ws + o); o += 4096;   // 64x128
  unsigned short* Wp3 = (unsigned short*)(ws + o); o += 16384;  // 128x256
  o = (o + 63) & ~(size_t)63;
  unsigned short* bufA = (unsigned short*)(ws + o); o += (size_t)N * 32;  // t1 / P2 (64ch)
  unsigned short* bufB = (unsigned short*)(ws + o); o += (size_t)N * 32;  // h2 (64ch)
  unsigned short* bufC = (unsigned short*)(ws + o); o += (size_t)N * 64;  // h3 (128ch)
  unsigned short* bufD = (unsigned short*)(ws + o); o += (size_t)N * 64;  // P3 (128ch)
  unsigned short* bufE = (unsigned short*)(ws + o); o += (size_t)N * 128; // h4 (256ch)

  hipMemsetAsync(cnt, 0, (size_t)N * sizeof(int), stream);
  hipMemsetAsync(pooled, 0, 2048 * sizeof(float), stream);

  k_hist<<<2048, 256, 0, stream>>>(ei, cnt, E);
  k_scan1<<<nb, 256, 0, stream>>>(cnt, row_tmp, bsum, N);
  k_scan2<<<1, 1024, 0, stream>>>(bsum, nb);
  k_scan3<<<nb, 256, 0, stream>>>(row_tmp, bsum, cnt, batch, dis, row_ptr,
                                  cursor, gstart, N, E);
  k_fill<<<2048, 256, 0, stream>>>(ei, cursor, col, E);
  k_packall<<<24, 256, 0, stream>>>(W1, W2, W3, Wp1, Wp2, Wp3);

  const int ablocks = (N + 3) / 4;
  const int mblocks = (N + 63) / 64;
  // L1: t1 = x @ W1 (fp32 in, raw out); h2 = relu(agg(t1) + b1)
  k_mm<128, 64, true, false><<<mblocks, 256, 0, stream>>>(x, Wp1, nullptr, bufA, N);
  k_agg64<true><<<ablocks, 256, 0, stream>>>(row_ptr, col, dis, bufA, b1, bufB, N);
  // L2: P2 = agg(h2); h3 = relu(P2 @ W2 + b2)
  k_agg64<false><<<ablocks, 256, 0, stream>>>(row_ptr, col, dis, bufB, nullptr, bufA, N);
  k_mm<64, 128, false, true><<<mblocks, 256, 0, stream>>>(bufA, Wp2, b2, bufC, N);
  // L3: P3 = agg(h3); h4 = relu(P3 @ W3 + b3)
  k_agg128<<<ablocks, 256, 0, stream>>>(row_ptr, col, dis, bufC, bufD, N);
  k_mm<128, 256, false, true><<<mblocks, 256, 0, stream>>>(bufD, Wp3, b3, bufE, N);

  k_pool2<<<dim3(128, 8), 256, 0, stream>>>(bufE, gstart, pooled);
  k_final<<<1, 256, 0, stream>>>(pooled, gstart, Wfc, bfc, out);
}

// Round 8
// 391.189 us; speedup vs baseline: 10.2265x; 1.0753x over previous
//
#include <hip/hip_runtime.h>
#include <hip/hip_bf16.h>

typedef __attribute__((ext_vector_type(8))) short short8v;   // 8 bf16 (4 VGPR)
typedef __attribute__((ext_vector_type(4))) float f32x4;

static __device__ __forceinline__ unsigned short f2bf(float f) {
  __hip_bfloat16 b = __float2bfloat16(f);  // round-to-nearest-even
  return *reinterpret_cast<unsigned short*>(&b);
}
static __device__ __forceinline__ float bf2f(unsigned short u) {
  unsigned int x = ((unsigned int)u) << 16;
  return __builtin_bit_cast(float, x);
}
static __device__ __forceinline__ float bflo(unsigned int u) {
  return __builtin_bit_cast(float, u << 16);
}
static __device__ __forceinline__ float bfhi(unsigned int u) {
  return __builtin_bit_cast(float, u & 0xffff0000u);
}

// ---------------- in-degree histogram over dst ----------------------------
__global__ __launch_bounds__(256) void k_hist(const int* __restrict__ ei,
                                              int* __restrict__ cnt, int E) {
  int stride = gridDim.x * blockDim.x;
  for (int i = blockIdx.x * blockDim.x + threadIdx.x; i < E; i += stride)
    atomicAdd(&cnt[ei[E + i]], 1);
}

// ---------------- exclusive scan of cnt -> row_ptr ------------------------
__global__ __launch_bounds__(256) void k_scan1(const int* __restrict__ cnt,
                                               int* __restrict__ row_tmp,
                                               int* __restrict__ bsum, int N) {
  __shared__ int sd[256];
  const int tid = threadIdx.x;
  const int i = blockIdx.x * 256 + tid;
  int v = (i < N) ? cnt[i] : 0;
  sd[tid] = v;
  __syncthreads();
#pragma unroll
  for (int off = 1; off < 256; off <<= 1) {
    int t = (tid >= off) ? sd[tid - off] : 0;
    __syncthreads();
    sd[tid] += t;
    __syncthreads();
  }
  if (i < N) row_tmp[i] = sd[tid] - v;  // exclusive
  if (tid == 255) bsum[blockIdx.x] = sd[255];
}

__global__ __launch_bounds__(1024) void k_scan2(int* __restrict__ bsum, int nb) {
  __shared__ int sd[1024];
  const int t = threadIdx.x;
  int v = (t < nb) ? bsum[t] : 0;
  sd[t] = v;
  __syncthreads();
#pragma unroll
  for (int off = 1; off < 1024; off <<= 1) {
    int x = (t >= off) ? sd[t - off] : 0;
    __syncthreads();
    sd[t] += x;
    __syncthreads();
  }
  if (t < nb) bsum[t] = sd[t] - v;  // exclusive
}

// row_ptr + dis + graph boundaries + bucket cursors, one pass over N
__global__ __launch_bounds__(256) void k_scan3(const int* __restrict__ row_tmp,
                                               const int* __restrict__ bsum,
                                               const int* __restrict__ cnt,
                                               const int* __restrict__ batch,
                                               float* __restrict__ dis,
                                               int* __restrict__ row_ptr,
                                               int* __restrict__ bucket_cur,
                                               int* __restrict__ gstart, int N,
                                               int E) {
  const int i = blockIdx.x * 256 + threadIdx.x;
  if (i < N) {
    int rp = row_tmp[i] + bsum[i >> 8];
    row_ptr[i] = rp;
    if ((i & 255) == 0) bucket_cur[i >> 8] = rp;  // bucket = dst>>8
    dis[i] = 1.0f / sqrtf((float)cnt[i] + 1.0f);
    int b = batch[i];
    if (i == 0) {
      for (int g = 0; g <= b; ++g) gstart[g] = 0;
    } else {
      int p = batch[i - 1];
      for (int g = p + 1; g <= b; ++g) gstart[g] = i;
    }
    if (i == N - 1)
      for (int g = b + 1; g <= 8; ++g) gstart[g] = N;
  }
  if (i == 0) row_ptr[N] = E;
}

// ------- bucketize edges into dst>>8 regions as packed (s,d) pairs --------
// per block: 2048 edges; rank via LDS atomics; one global atomic per digit.
__global__ __launch_bounds__(256) void k_b3(const int* __restrict__ ei,
                                            int* __restrict__ bucket_cur,
                                            uint2* __restrict__ pairs, int E) {
  __shared__ int cntD[512];
  __shared__ int gbase[512];
  const int t = threadIdx.x;
  for (int i = t; i < 512; i += 256) cntD[i] = 0;
  __syncthreads();
  const int base = blockIdx.x * 2048;
  int s[8], d[8], rk[8];
#pragma unroll
  for (int i = 0; i < 8; ++i) {
    int e = base + i * 256 + t;
    if (e < E) {
      s[i] = ei[e];
      d[i] = ei[E + e];
      rk[i] = atomicAdd(&cntD[d[i] >> 8], 1);
    }
  }
  __syncthreads();
  for (int i = t; i < 512; i += 256)
    if (cntD[i] > 0) gbase[i] = atomicAdd(&bucket_cur[i], cntD[i]);
  __syncthreads();
#pragma unroll
  for (int i = 0; i < 8; ++i) {
    int e = base + i * 256 + t;
    if (e < E)
      pairs[gbase[d[i] >> 8] + rk[i]] = make_uint2((unsigned)s[i], (unsigned)d[i]);
  }
}

// ------- per-bucket exact CSR fill: block-local col writes ----------------
__global__ __launch_bounds__(256) void k_b4(const int* __restrict__ row_ptr,
                                            const uint2* __restrict__ pairs,
                                            int* __restrict__ col, int N) {
  __shared__ int curL[257];
  const int n0 = blockIdx.x << 8;
  const int nn = min(256, N - n0);
  const int t = threadIdx.x;
  for (int i = t; i <= nn; i += 256) curL[i] = row_ptr[n0 + i];  // inclusive!
  __syncthreads();
  const int p0 = curL[0], p1 = curL[nn];
  __syncthreads();
  for (int idx = p0 + t; idx < p1; idx += 256) {
    uint2 pr = pairs[idx];
    int pos = atomicAdd(&curL[(int)pr.y - n0], 1);
    col[pos] = (int)pr.x;
  }
}

// ---------------- pack W (KxM fp32) into B-fragment layout ----------------
static __device__ __forceinline__ void pack_one(const float* __restrict__ W,
                                                unsigned short* __restrict__ Wp,
                                                int K, int M, int t) {
  int KT = K >> 5;
  int lane = t & 63;
  int tile = t >> 6;
  int kt = tile % KT;
  int ct = tile / KT;
  int c = ct * 16 + (lane & 15);
  int k0 = kt * 32 + (lane >> 4) * 8;
  unsigned short v[8];
#pragma unroll
  for (int j = 0; j < 8; ++j) v[j] = f2bf(W[(size_t)(k0 + j) * M + c]);
  ushort4* dst = (ushort4*)&Wp[(size_t)t * 8];
  dst[0] = make_ushort4(v[0], v[1], v[2], v[3]);
  dst[1] = make_ushort4(v[4], v[5], v[6], v[7]);
}

__global__ __launch_bounds__(256) void k_packall(
    const float* __restrict__ W1, const float* __restrict__ W2,
    const float* __restrict__ W3, unsigned short* __restrict__ Wp1,
    unsigned short* __restrict__ Wp2, unsigned short* __restrict__ Wp3) {
  int t = blockIdx.x * 256 + threadIdx.x;
  if (t < 1024)
    pack_one(W1, Wp1, 128, 64, t);          // 4*4*64 frags
  else if (t < 2048)
    pack_one(W2, Wp2, 64, 128, t - 1024);   // 8*2*64
  else if (t < 6144)
    pack_one(W3, Wp3, 128, 256, t - 2048);  // 16*4*64
}

// ------- CSR agg, M=64: wave/dst; 8 sub-waves x 8 lanes x 8ch (16B loads) -
// P[d] = (EPI? relu(.+b):.) of Hin[d]*dis_d^2 + sum Hin[s]*dis_s*dis_d
template <bool EPI>
__global__ __launch_bounds__(256) void k_agg64(const int* __restrict__ row_ptr,
                                               const int* __restrict__ col,
                                               const float* __restrict__ dis,
                                               const unsigned short* __restrict__ Hin,
                                               const float* __restrict__ bias,
                                               unsigned short* __restrict__ Pout,
                                               int N) {
  const int lane = threadIdx.x & 63;
  int d = blockIdx.x * 4 + (threadIdx.x >> 6);
  if (d >= N) return;
  const int q = lane >> 3;   // sub-wave 0..7, one edge each
  const int cl = lane & 7;   // 8 lanes x 8ch = 64 channels
  const int cb = cl * 8;
  const float disd = dis[d];
  const int beg = row_ptr[d];
  const int end = row_ptr[d + 1];
  const int deg = end - beg;
  const int nedge = min(deg, 64);

  // lane-parallel prefetch of all indices + norm weights for this row
  int s_l = d;
  float w_l = 0.f;
  if (lane < nedge) {
    s_l = col[beg + lane];
    w_l = dis[s_l] * disd;
  }

  float acc[8];
#pragma unroll
  for (int k = 0; k < 8; ++k) acc[k] = 0.f;
  if (q == 0) {  // self-loop on sub-wave 0
    uint4 u = *(const uint4*)&Hin[(size_t)d * 64 + cb];
    const float sc = disd * disd;
    acc[0] = bflo(u.x) * sc; acc[1] = bfhi(u.x) * sc;
    acc[2] = bflo(u.y) * sc; acc[3] = bfhi(u.y) * sc;
    acc[4] = bflo(u.z) * sc; acc[5] = bfhi(u.z) * sc;
    acc[6] = bflo(u.w) * sc; acc[7] = bfhi(u.w) * sc;
  }

  const int padded = (nedge + 15) & ~15;  // 16 edges per iter (8 subwaves x2)
  for (int base = 0; base < padded; base += 16) {
    int e0 = base + q, e1 = base + 8 + q;
    int s0 = __shfl(s_l, e0, 64);
    float w0 = __shfl(w_l, e0, 64);
    int s1 = __shfl(s_l, e1, 64);
    float w1 = __shfl(w_l, e1, 64);
    if (e0 >= nedge) { s0 = d; w0 = 0.f; }
    if (e1 >= nedge) { s1 = d; w1 = 0.f; }
    uint4 u0 = *(const uint4*)&Hin[(size_t)s0 * 64 + cb];
    uint4 u1 = *(const uint4*)&Hin[(size_t)s1 * 64 + cb];
    acc[0] = fmaf(bflo(u0.x), w0, acc[0]); acc[1] = fmaf(bfhi(u0.x), w0, acc[1]);
    acc[2] = fmaf(bflo(u0.y), w0, acc[2]); acc[3] = fmaf(bfhi(u0.y), w0, acc[3]);
    acc[4] = fmaf(bflo(u0.z), w0, acc[4]); acc[5] = fmaf(bfhi(u0.z), w0, acc[5]);
    acc[6] = fmaf(bflo(u0.w), w0, acc[6]); acc[7] = fmaf(bfhi(u0.w), w0, acc[7]);
    acc[0] = fmaf(bflo(u1.x), w1, acc[0]); acc[1] = fmaf(bfhi(u1.x), w1, acc[1]);
    acc[2] = fmaf(bflo(u1.y), w1, acc[2]); acc[3] = fmaf(bfhi(u1.y), w1, acc[3]);
    acc[4] = fmaf(bflo(u1.z), w1, acc[4]); acc[5] = fmaf(bfhi(u1.z), w1, acc[5]);
    acc[6] = fmaf(bflo(u1.w), w1, acc[6]); acc[7] = fmaf(bfhi(u1.w), w1, acc[7]);
  }
  if (deg > 64) {  // essentially never (Poisson deg~8); correctness tail
    for (int j = beg + 64 + q; j < end; j += 8) {
      int s = col[j];
      float w = dis[s] * disd;
      uint4 u = *(const uint4*)&Hin[(size_t)s * 64 + cb];
      acc[0] = fmaf(bflo(u.x), w, acc[0]); acc[1] = fmaf(bfhi(u.x), w, acc[1]);
      acc[2] = fmaf(bflo(u.y), w, acc[2]); acc[3] = fmaf(bfhi(u.y), w, acc[3]);
      acc[4] = fmaf(bflo(u.z), w, acc[4]); acc[5] = fmaf(bfhi(u.z), w, acc[5]);
      acc[6] = fmaf(bflo(u.w), w, acc[6]); acc[7] = fmaf(bfhi(u.w), w, acc[7]);
    }
  }

#pragma unroll
  for (int k = 0; k < 8; ++k) {
    acc[k] += __shfl_xor(acc[k], 8, 64);
    acc[k] += __shfl_xor(acc[k], 16, 64);
    acc[k] += __shfl_xor(acc[k], 32, 64);
  }
  if (q == 0) {
    if (EPI) {
#pragma unroll
      for (int k = 0; k < 8; ++k) acc[k] = fmaxf(acc[k] + bias[cb + k], 0.f);
    }
    uint4 o;
    o.x = (unsigned)f2bf(acc[0]) | ((unsigned)f2bf(acc[1]) << 16);
    o.y = (unsigned)f2bf(acc[2]) | ((unsigned)f2bf(acc[3]) << 16);
    o.z = (unsigned)f2bf(acc[4]) | ((unsigned)f2bf(acc[5]) << 16);
    o.w = (unsigned)f2bf(acc[6]) | ((unsigned)f2bf(acc[7]) << 16);
    *(uint4*)&Pout[(size_t)d * 64 + cb] = o;
  }
}

// ------- CSR agg, M=128: wave/dst; 4 sub-waves x 16 lanes x 8ch -----------
__global__ __launch_bounds__(256) void k_agg128(const int* __restrict__ row_ptr,
                                                const int* __restrict__ col,
                                                const float* __restrict__ dis,
                                                const unsigned short* __restrict__ Hin,
                                                unsigned short* __restrict__ Pout,
                                                int N) {
  const int lane = threadIdx.x & 63;
  int d = blockIdx.x * 4 + (threadIdx.x >> 6);
  if (d >= N) return;
  const int q = lane >> 4;    // sub-wave 0..3
  const int cl = lane & 15;   // 16 lanes x 8ch = 128 channels
  const int cb = cl * 8;
  const float disd = dis[d];
  const int beg = row_ptr[d];
  const int end = row_ptr[d + 1];
  const int deg = end - beg;
  const int nedge = min(deg, 64);

  int s_l = d;
  float w_l = 0.f;
  if (lane < nedge) {
    s_l = col[beg + lane];
    w_l = dis[s_l] * disd;
  }

  float acc[8];
#pragma unroll
  for (int k = 0; k < 8; ++k) acc[k] = 0.f;
  if (q == 0) {  // self-loop
    uint4 u = *(const uint4*)&Hin[(size_t)d * 128 + cb];
    const float sc = disd * disd;
    acc[0] = bflo(u.x) * sc; acc[1] = bfhi(u.x) * sc;
    acc[2] = bflo(u.y) * sc; acc[3] = bfhi(u.y) * sc;
    acc[4] = bflo(u.z) * sc; acc[5] = bfhi(u.z) * sc;
    acc[6] = bflo(u.w) * sc; acc[7] = bfhi(u.w) * sc;
  }

  const int padded = (nedge + 7) & ~7;  // 8 edges per iter (4 subwaves x2)
  for (int base = 0; base < padded; base += 8) {
    int e0 = base + q, e1 = base + 4 + q;
    int s0 = __shfl(s_l, e0, 64);
    float w0 = __shfl(w_l, e0, 64);
    int s1 = __shfl(s_l, e1, 64);
    float w1 = __shfl(w_l, e1, 64);
    if (e0 >= nedge) { s0 = d; w0 = 0.f; }
    if (e1 >= nedge) { s1 = d; w1 = 0.f; }
    uint4 u0 = *(const uint4*)&Hin[(size_t)s0 * 128 + cb];
    uint4 u1 = *(const uint4*)&Hin[(size_t)s1 * 128 + cb];
    acc[0] = fmaf(bflo(u0.x), w0, acc[0]); acc[1] = fmaf(bfhi(u0.x), w0, acc[1]);
    acc[2] = fmaf(bflo(u0.y), w0, acc[2]); acc[3] = fmaf(bfhi(u0.y), w0, acc[3]);
    acc[4] = fmaf(bflo(u0.z), w0, acc[4]); acc[5] = fmaf(bfhi(u0.z), w0, acc[5]);
    acc[6] = fmaf(bflo(u0.w), w0, acc[6]); acc[7] = fmaf(bfhi(u0.w), w0, acc[7]);
    acc[0] = fmaf(bflo(u1.x), w1, acc[0]); acc[1] = fmaf(bfhi(u1.x), w1, acc[1]);
    acc[2] = fmaf(bflo(u1.y), w1, acc[2]); acc[3] = fmaf(bfhi(u1.y), w1, acc[3]);
    acc[4] = fmaf(bflo(u1.z), w1, acc[4]); acc[5] = fmaf(bfhi(u1.z), w1, acc[5]);
    acc[6] = fmaf(bflo(u1.w), w1, acc[6]); acc[7] = fmaf(bfhi(u1.w), w1, acc[7]);
  }
  if (deg > 64) {
    for (int j = beg + 64 + q; j < end; j += 4) {
      int s = col[j];
      float w = dis[s] * disd;
      uint4 u = *(const uint4*)&Hin[(size_t)s * 128 + cb];
      acc[0] = fmaf(bflo(u.x), w, acc[0]); acc[1] = fmaf(bfhi(u.x), w, acc[1]);
      acc[2] = fmaf(bflo(u.y), w, acc[2]); acc[3] = fmaf(bfhi(u.y), w, acc[3]);
      acc[4] = fmaf(bflo(u.z), w, acc[4]); acc[5] = fmaf(bfhi(u.z), w, acc[5]);
      acc[6] = fmaf(bflo(u.w), w, acc[6]); acc[7] = fmaf(bfhi(u.w), w, acc[7]);
    }
  }

#pragma unroll
  for (int k = 0; k < 8; ++k) {
    acc[k] += __shfl_xor(acc[k], 16, 64);
    acc[k] += __shfl_xor(acc[k], 32, 64);
  }
  if (q == 0) {
    uint4 o;
    o.x = (unsigned)f2bf(acc[0]) | ((unsigned)f2bf(acc[1]) << 16);
    o.y = (unsigned)f2bf(acc[2]) | ((unsigned)f2bf(acc[3]) << 16);
    o.z = (unsigned)f2bf(acc[4]) | ((unsigned)f2bf(acc[5]) << 16);
    o.w = (unsigned)f2bf(acc[6]) | ((unsigned)f2bf(acc[7]) << 16);
    *(uint4*)&Pout[(size_t)d * 128 + cb] = o;
  }
}

// ---------------- MFMA GEMM: Hout = [relu](A @ W [+ b]), bf16 out ---------
// A frag: lane holds A[row0+(lane&15)][kt*32+(lane>>4)*8 + 0..7]
// D frag: row=(lane>>4)*4+reg, col=lane&15
template <int K, int M, bool F32IN, bool BIAS>
__global__ __launch_bounds__(256) void k_mm(const void* __restrict__ Ap,
                                            const unsigned short* __restrict__ Wp,
                                            const float* __restrict__ bias,
                                            unsigned short* __restrict__ Hout,
                                            int N) {
  constexpr int KT = K / 32, CT = M / 16;
  const int lane = threadIdx.x & 63;
  const int wid = threadIdx.x >> 6;
  int row0 = (blockIdx.x * 4 + wid) * 16;
  row0 = __builtin_amdgcn_readfirstlane(row0);
  if (row0 >= N) return;
  const int r = lane & 15;
  const int kh = lane >> 4;

  int arow = row0 + r;
  if (arow >= N) arow = N - 1;

  f32x4 acc[CT];
#pragma unroll
  for (int ct = 0; ct < CT; ++ct) acc[ct] = (f32x4){0.f, 0.f, 0.f, 0.f};

#pragma unroll
  for (int kt = 0; kt < KT; ++kt) {
    short8v a;
    if (F32IN) {
      const float* Af = (const float*)Ap;
      const float* p = &Af[(size_t)arow * K + kt * 32 + kh * 8];
      float4 f0 = *(const float4*)p;
      float4 f1 = *(const float4*)(p + 4);
      a[0] = (short)f2bf(f0.x); a[1] = (short)f2bf(f0.y);
      a[2] = (short)f2bf(f0.z); a[3] = (short)f2bf(f0.w);
      a[4] = (short)f2bf(f1.x); a[5] = (short)f2bf(f1.y);
      a[6] = (short)f2bf(f1.z); a[7] = (short)f2bf(f1.w);
    } else {
      const unsigned short* Ab = (const unsigned short*)Ap;
      a = *(const short8v*)&Ab[(size_t)arow * K + kt * 32 + kh * 8];
    }
#pragma unroll
    for (int ct = 0; ct < CT; ++ct) {
      short8v b = *(const short8v*)&Wp[(size_t)((ct * KT + kt) * 64 + lane) * 8];
      acc[ct] = __builtin_amdgcn_mfma_f32_16x16x32_bf16(a, b, acc[ct], 0, 0, 0);
    }
  }

  const int orow0 = row0 + kh * 4;
#pragma unroll
  for (int ct = 0; ct < CT; ++ct) {
    const int c = ct * 16 + r;
    const float bv = BIAS ? bias[c] : 0.f;
#pragma unroll
    for (int reg = 0; reg < 4; ++reg) {
      int row = orow0 + reg;
      if (row < N) {
        float v = acc[ct][reg] + bv;
        if (BIAS) v = fmaxf(v, 0.f);
        Hout[(size_t)row * M + c] = f2bf(v);
      }
    }
  }
}

// ---------------- pooling: per-graph segmented sum over sorted rows -------
__global__ __launch_bounds__(256) void k_pool2(const unsigned short* __restrict__ H4,
                                               const int* __restrict__ gstart,
                                               float* __restrict__ pooled) {
  __shared__ float sd[8][256];
  const int g = blockIdx.y;
  const int s = gstart[g], e = gstart[g + 1];
  if (s >= e) return;  // uniform per block
  const int PB = gridDim.x;
  const int chunk = (e - s + PB - 1) / PB;
  const int r0 = s + blockIdx.x * chunk;
  const int r1 = min(e, r0 + chunk);

  const int t = threadIdx.x;
  const int rs = t >> 5;
  const int cl = t & 31;
  const int cb = cl * 8;

  float a[8];
#pragma unroll
  for (int k = 0; k < 8; ++k) a[k] = 0.f;

  for (int r = r0 + rs; r < r1; r += 8) {
    uint4 u = *(const uint4*)&H4[(size_t)r * 256 + cb];
    a[0] += bflo(u.x); a[1] += bfhi(u.x);
    a[2] += bflo(u.y); a[3] += bfhi(u.y);
    a[4] += bflo(u.z); a[5] += bfhi(u.z);
    a[6] += bflo(u.w); a[7] += bfhi(u.w);
  }
#pragma unroll
  for (int k = 0; k < 8; ++k) sd[rs][cb + k] = a[k];
  __syncthreads();
  float v = 0.f;
#pragma unroll
  for (int q = 0; q < 8; ++q) v += sd[q][t];
  atomicAdd(&pooled[g * 256 + t], v);
}

// ---------------- final FC: out[g] = pooled[g]/cnt . Wfc + bfc ------------
__global__ __launch_bounds__(256) void k_final(const float* __restrict__ pooled,
                                               const int* __restrict__ gstart,
                                               const float* __restrict__ Wfc,
                                               const float* __restrict__ bfc,
                                               float* __restrict__ out) {
  __shared__ float red[4];
  const int t = threadIdx.x;
  for (int g = 0; g < 8; ++g) {
    float cg = (float)(gstart[g + 1] - gstart[g]);
    float v = pooled[g * 256 + t] / cg * Wfc[t];
#pragma unroll
    for (int off = 32; off > 0; off >>= 1) v += __shfl_down(v, off, 64);
    if ((t & 63) == 0) red[t >> 6] = v;
    __syncthreads();
    if (t == 0) out[g] = red[0] + red[1] + red[2] + red[3] + bfc[0];
    __syncthreads();
  }
}

extern "C" void kernel_launch(void* const* d_in, const int* in_sizes, int n_in,
                              void* d_out, int out_size, void* d_ws,
                              size_t ws_size, hipStream_t stream) {
  const float* x = (const float*)d_in[0];
  const int* ei = (const int*)d_in[1];
  const int* batch = (const int*)d_in[2];
  const float* W1 = (const float*)d_in[3];
  const float* b1 = (const float*)d_in[4];
  const float* W2 = (const float*)d_in[5];
  const float* b2 = (const float*)d_in[6];
  const float* W3 = (const float*)d_in[7];
  const float* b3 = (const float*)d_in[8];
  const float* Wfc = (const float*)d_in[9];
  const float* bfc = (const float*)d_in[10];
  float* out = (float*)d_out;

  const int N = in_sizes[0] / 128;
  const int E = in_sizes[1] / 2;
  const int nb = (N + 255) / 256;
  const int nbk = (N + 255) >> 8;  // dst buckets (256 nodes each)

  // -------- workspace layout (4-byte units), ~140 MB total --------
  float* ws = (float*)d_ws;
  size_t o = 0;
  float* dis = ws + o;            o += (size_t)N;
  int* cnt = (int*)(ws + o);      o += (size_t)N;
  int* row_tmp = (int*)(ws + o);  o += (size_t)N;
  int* bsum = (int*)(ws + o);     o += 1024;
  int* row_ptr = (int*)(ws + o);  o += (size_t)N + 1;
  int* bucket_cur = (int*)(ws + o); o += 512;
  int* col = (int*)(ws + o);      o += (size_t)E;
  uint2* pairs = (uint2*)(ws + o); o += (size_t)E * 2;
  float* pooled = ws + o;         o += 2048;
  int* gstart = (int*)(ws + o);   o += 16;
  unsigned short* Wp1 = (unsigned short*)(ws + o); o += 4096;   // 128x64 bf16
  unsigned short* Wp2 = (unsigned short*)(ws + o); o += 4096;   // 64x128
  unsigned short* Wp3 = (unsigned short*)(ws + o); o += 16384;  // 128x256
  o = (o + 63) & ~(size_t)63;
  unsigned short* bufA = (unsigned short*)(ws + o); o += (size_t)N * 32;  // t1 / P2 (64ch)
  unsigned short* bufB = (unsigned short*)(ws + o); o += (size_t)N * 32;  // h2 (64ch)
  unsigned short* bufC = (unsigned short*)(ws + o); o += (size_t)N * 64;  // h3 (128ch)
  unsigned short* bufD = (unsigned short*)(ws + o); o += (size_t)N * 64;  // P3 (128ch)
  unsigned short* bufE = (unsigned short*)(ws + o); o += (size_t)N * 128; // h4 (256ch)

  hipMemsetAsync(cnt, 0, (size_t)N * sizeof(int), stream);
  hipMemsetAsync(pooled, 0, 2048 * sizeof(float), stream);

  k_hist<<<2048, 256, 0, stream>>>(ei, cnt, E);
  k_scan1<<<nb, 256, 0, stream>>>(cnt, row_tmp, bsum, N);
  k_scan2<<<1, 1024, 0, stream>>>(bsum, nb);
  k_scan3<<<nb, 256, 0, stream>>>(row_tmp, bsum, cnt, batch, dis, row_ptr,
                                  bucket_cur, gstart, N, E);
  k_b3<<<(E + 2047) / 2048, 256, 0, stream>>>(ei, bucket_cur, pairs, E);
  k_b4<<<nbk, 256, 0, stream>>>(row_ptr, pairs, col, N);
  k_packall<<<24, 256, 0, stream>>>(W1, W2, W3, Wp1, Wp2, Wp3);

  const int ablocks = (N + 3) / 4;
  const int mblocks = (N + 63) / 64;
  // L1: t1 = x @ W1 (fp32 in, raw out); h2 = relu(agg(t1) + b1)
  k_mm<128, 64, true, false><<<mblocks, 256, 0, stream>>>(x, Wp1, nullptr, bufA, N);
  k_agg64<true><<<ablocks, 256, 0, stream>>>(row_ptr, col, dis, bufA, b1, bufB, N);
  // L2: P2 = agg(h2); h3 = relu(P2 @ W2 + b2)
  k_agg64<false><<<ablocks, 256, 0, stream>>>(row_ptr, col, dis, bufB, nullptr, bufA, N);
  k_mm<64, 128, false, true><<<mblocks, 256, 0, stream>>>(bufA, Wp2, b2, bufC, N);
  // L3: P3 = agg(h3); h4 = relu(P3 @ W3 + b3)
  k_agg128<<<ablocks, 256, 0, stream>>>(row_ptr, col, dis, bufC, bufD, N);
  k_mm<128, 256, false, true><<<mblocks, 256, 0, stream>>>(bufD, Wp3, b3, bufE, N);

  k_pool2<<<dim3(128, 8), 256, 0, stream>>>(bufE, gstart, pooled);
  k_final<<<1, 256, 0, stream>>>(pooled, gstart, Wfc, bfc, out);
}